// Round 13
// baseline (7809.630 us; speedup 1.0000x reference)
//
#include <hip/hip_runtime.h>
#include <hip/hip_bf16.h>
#include <cstdint>

#define B_   8
#define S_   512
#define D_   768
#define C_   9
#define BS_  4096   // B*S

typedef unsigned long long u64;
typedef unsigned short ushort_t;
typedef short bf16x8 __attribute__((ext_vector_type(8)));
typedef float f32x4 __attribute__((ext_vector_type(4)));
typedef __attribute__((address_space(1))) const void gvoid_t;
typedef __attribute__((address_space(3))) void svoid_t;

// ---------------------------------------------------------------------------
// embedding gather
// ---------------------------------------------------------------------------
__global__ __launch_bounds__(192) void k_embed(const int* __restrict__ ids,
                                               const float* __restrict__ emb,
                                               float* __restrict__ x) {
  int row = blockIdx.x;
  int id = ids[row];
  const float4* src = (const float4*)(emb + (size_t)id * D_);
  float4* dst = (float4*)(x + (size_t)row * D_);
  dst[threadIdx.x] = src[threadIdx.x];
}

// ---------------------------------------------------------------------------
// fp32 GEMM (single-buffer + XCD swizzle) — fallback path only.
// ---------------------------------------------------------------------------
#define GIDX(k, m) ((k)*144 + (m) + (((m) >> 5) << 2))

__global__ __launch_bounds__(256) void k_gemm(const float* __restrict__ A,
                                              const float* __restrict__ W,
                                              const float* __restrict__ bias,
                                              float* __restrict__ C,
                                              int M, int N, int K, int act, int mode) {
  __shared__ float As[2304];
  __shared__ float Bs[2304];
  int nwg = gridDim.x * gridDim.y;
  int lin = blockIdx.y * gridDim.x + blockIdx.x;
  int cpx = nwg >> 3;
  int swz = (lin & 7) * cpx + (lin >> 3);
  int bxs = swz % gridDim.x, bys = swz / gridDim.x;
  int bm0 = bys * 128, bn0 = bxs * 128;
  int tid = threadIdx.x;
  int tm = tid >> 4, tn = tid & 15;
  float acc[8][8];
#pragma unroll
  for (int i = 0; i < 8; ++i)
#pragma unroll
    for (int j = 0; j < 8; ++j) acc[i][j] = 0.f;

  for (int k0 = 0; k0 < K; k0 += 16) {
    __syncthreads();
#pragma unroll
    for (int j = 0; j < 2; ++j) {
      int f4 = tid + j * 256;
      int r = f4 >> 2;
      int kq = (f4 & 3) * 4;
      float4 va = *(const float4*)(A + (size_t)(bm0 + r) * K + k0 + kq);
      As[GIDX(kq + 0, r)] = va.x; As[GIDX(kq + 1, r)] = va.y;
      As[GIDX(kq + 2, r)] = va.z; As[GIDX(kq + 3, r)] = va.w;
      float4 vb = *(const float4*)(W + (size_t)(bn0 + r) * K + k0 + kq);
      Bs[GIDX(kq + 0, r)] = vb.x; Bs[GIDX(kq + 1, r)] = vb.y;
      Bs[GIDX(kq + 2, r)] = vb.z; Bs[GIDX(kq + 3, r)] = vb.w;
    }
    __syncthreads();
#pragma unroll
    for (int kk = 0; kk < 16; ++kk) {
      float a[8], b[8];
      *(float4*)&a[0] = *(const float4*)&As[GIDX(kk, tm * 8)];
      *(float4*)&a[4] = *(const float4*)&As[GIDX(kk, tm * 8 + 4)];
      *(float4*)&b[0] = *(const float4*)&Bs[GIDX(kk, tn * 8)];
      *(float4*)&b[4] = *(const float4*)&Bs[GIDX(kk, tn * 8 + 4)];
#pragma unroll
      for (int i = 0; i < 8; ++i)
#pragma unroll
        for (int j = 0; j < 8; ++j) acc[i][j] += a[i] * b[j];
    }
  }

  float bv[8];
#pragma unroll
  for (int j = 0; j < 8; ++j) bv[j] = bias[bn0 + tn * 8 + j];
#pragma unroll
  for (int i = 0; i < 8; ++i) {
    int row = bm0 + tm * 8 + i;
    float o[8];
#pragma unroll
    for (int j = 0; j < 8; ++j) {
      float v = acc[i][j] + bv[j];
      if (act == 1) v = fmaxf(v, 0.f);
      else if (act == 2) v = 1.f / (1.f + expf(-v));
      o[j] = v;
    }
    if (mode == 0) {
      float* cp = C + (size_t)row * N + bn0 + tn * 8;
      *(float4*)cp = make_float4(o[0], o[1], o[2], o[3]);
      *(float4*)(cp + 4) = make_float4(o[4], o[5], o[6], o[7]);
    } else {
      int bb = row >> 9, t = row & 511;
#pragma unroll
      for (int j = 0; j < 8; ++j) {
        unsigned n = bn0 + tn * 8 + j;
        unsigned dir = n / 3072u;
        unsigned n2 = n - dir * 3072u;
        unsigned g = n2 / 768u;
        unsigned rem = n2 - g * 768u;
        unsigned grp = rem >> 3, u = rem & 7;
        C[(((size_t)(dir * 512 + t) * 96 + grp) << 8) + u * 32 + g * 8 + bb] = o[j];
      }
    }
  }
}

// ---------------------------------------------------------------------------
// split-bf16 conversion: dst[m][3K] = mode0: [hi|lo|hi] (A)  mode1: [hi|hi|lo]
// ---------------------------------------------------------------------------
__device__ inline ushort_t f2bf_bits(float x) {
  __hip_bfloat16 h = __float2bfloat16(x);
  return __builtin_bit_cast(ushort_t, h);
}
__device__ inline float bf2f(ushort_t b) {
  return __bfloat162float(__builtin_bit_cast(__hip_bfloat16, b));
}

__global__ __launch_bounds__(256) void k_cvt(const float* __restrict__ src,
                                             ushort_t* __restrict__ dst,
                                             int K, int total4, int mode) {
  int kq4 = K >> 2;
  for (int idx = blockIdx.x * 256 + threadIdx.x; idx < total4; idx += gridDim.x * 256) {
    int m = idx / kq4;
    int kq = (idx - m * kq4) * 4;
    float4 v = *(const float4*)(src + (size_t)m * K + kq);
    ushort4 hi, lo;
    hi.x = f2bf_bits(v.x); lo.x = f2bf_bits(v.x - bf2f(hi.x));
    hi.y = f2bf_bits(v.y); lo.y = f2bf_bits(v.y - bf2f(hi.y));
    hi.z = f2bf_bits(v.z); lo.z = f2bf_bits(v.z - bf2f(hi.z));
    hi.w = f2bf_bits(v.w); lo.w = f2bf_bits(v.w - bf2f(hi.w));
    ushort_t* base = dst + (size_t)m * 3 * K + kq;
    *(ushort4*)(base)         = hi;
    *(ushort4*)(base + K)     = mode ? hi : lo;
    *(ushort4*)(base + 2 * K) = mode ? lo : hi;
  }
}

// ---------------------------------------------------------------------------
// bf16 MFMA GEMM (unified). C = A'[M][Kp] @ W'[N][Kp]^T + bias.
// mode 0: row-major C with act; mode 1: lstm-gates layout.
// ---------------------------------------------------------------------------
__global__ __launch_bounds__(256) void k_mfma(const ushort_t* __restrict__ A,
                                              const ushort_t* __restrict__ W,
                                              const float* __restrict__ bias,
                                              float* __restrict__ C,
                                              int N, int Kp, int act, int mode) {
  __shared__ ushort_t Asb[128 * 64];
  __shared__ ushort_t Bsb[128 * 64];
  int nwg = gridDim.x * gridDim.y;
  int lin = blockIdx.y * gridDim.x + blockIdx.x;
  int cpx = nwg >> 3;
  int swz = (lin & 7) * cpx + (lin >> 3);
  int bn0 = (swz % gridDim.x) * 128, bm0 = (swz / gridDim.x) * 128;
  int tid = threadIdx.x;
  int w = tid >> 6, lane = tid & 63;
  int lr = lane & 15, lq = lane >> 4;

  f32x4 acc[2][8];
#pragma unroll
  for (int i = 0; i < 2; ++i)
#pragma unroll
    for (int j = 0; j < 8; ++j) acc[i][j] = (f32x4){0.f, 0.f, 0.f, 0.f};

  int srow0 = tid >> 3;
  int sc = tid & 7;

  for (int k0 = 0; k0 < Kp; k0 += 64) {
    __syncthreads();
#pragma unroll
    for (int it = 0; it < 4; ++it) {
      int row = it * 32 + srow0;
      int soff = (sc ^ (row & 7)) * 8;
      const ushort_t* ga = A + (size_t)(bm0 + row) * Kp + k0 + soff;
      const ushort_t* gb = W + (size_t)(bn0 + row) * Kp + k0 + soff;
      char* la = (char*)Asb + it * 4096 + (tid & 192) * 16;
      char* lb = (char*)Bsb + it * 4096 + (tid & 192) * 16;
      __builtin_amdgcn_global_load_lds((gvoid_t*)ga, (svoid_t*)la, 16, 0, 0);
      __builtin_amdgcn_global_load_lds((gvoid_t*)gb, (svoid_t*)lb, 16, 0, 0);
    }
    __syncthreads();
#pragma unroll
    for (int kf = 0; kf < 2; ++kf) {
      int c = kf * 4 + lq;
      int rowA0 = w * 32 + lr;
      int rowA1 = rowA0 + 16;
      bf16x8 a0 = *(const bf16x8*)&Asb[rowA0 * 64 + ((c ^ (rowA0 & 7)) << 3)];
      bf16x8 a1 = *(const bf16x8*)&Asb[rowA1 * 64 + ((c ^ (rowA1 & 7)) << 3)];
#pragma unroll
      for (int ns = 0; ns < 8; ++ns) {
        int rowB = ns * 16 + lr;
        bf16x8 b = *(const bf16x8*)&Bsb[rowB * 64 + ((c ^ (rowB & 7)) << 3)];
        acc[0][ns] = __builtin_amdgcn_mfma_f32_16x16x32_bf16(a0, b, acc[0][ns], 0, 0, 0);
        acc[1][ns] = __builtin_amdgcn_mfma_f32_16x16x32_bf16(a1, b, acc[1][ns], 0, 0, 0);
      }
    }
  }

  if (mode == 1) {
#pragma unroll
    for (int ns = 0; ns < 8; ++ns) {
      unsigned n = bn0 + ns * 16 + lr;
      unsigned dir = n / 3072u;
      unsigned n2 = n - dir * 3072u;
      unsigned g = n2 / 768u;
      unsigned rem = n2 - g * 768u;
      unsigned grp = rem >> 3, u = rem & 7;
      float bv = bias[n];
#pragma unroll
      for (int ms = 0; ms < 2; ++ms) {
#pragma unroll
        for (int r = 0; r < 4; ++r) {
          int m = bm0 + w * 32 + ms * 16 + lq * 4 + r;
          int bb = m >> 9, t = m & 511;
          C[(((size_t)(dir * 512 + t) * 96 + grp) << 8) + u * 32 + g * 8 + bb] =
              acc[ms][ns][r] + bv;
        }
      }
    }
  } else {
#pragma unroll
    for (int ns = 0; ns < 8; ++ns) {
      int col = bn0 + ns * 16 + lr;
      float bv = bias[col];
#pragma unroll
      for (int ms = 0; ms < 2; ++ms) {
#pragma unroll
        for (int r = 0; r < 4; ++r) {
          int m = bm0 + w * 32 + ms * 16 + lq * 4 + r;
          float v = acc[ms][ns][r] + bv;
          if (act == 1) v = fmaxf(v, 0.f);
          else if (act == 2) v = 1.f / (1.f + expf(-v));
          C[(size_t)m * N + col] = v;
        }
      }
    }
  }
}

// ---------------------------------------------------------------------------
// highway combine (in place)
// ---------------------------------------------------------------------------
__global__ __launch_bounds__(256) void k_highway(float* __restrict__ x,
                                                 const float* __restrict__ hh,
                                                 const float* __restrict__ tt) {
  const int n4 = BS_ * D_ / 4;
  for (int i = blockIdx.x * 256 + threadIdx.x; i < n4; i += gridDim.x * 256) {
    float4 xv = ((const float4*)x)[i];
    float4 hv = ((const float4*)hh)[i];
    float4 tv = ((const float4*)tt)[i];
    xv.x = tv.x * hv.x + (1.f - tv.x) * xv.x;
    xv.y = tv.y * hv.y + (1.f - tv.y) * xv.y;
    xv.z = tv.z * hv.z + (1.f - tv.z) * xv.z;
    xv.w = tv.w * hv.w + (1.f - tv.w) * xv.w;
    ((float4*)x)[i] = xv;
  }
}

// ---------------------------------------------------------------------------
// multi-head attention (unchanged)
// ---------------------------------------------------------------------------
__global__ __launch_bounds__(256) void k_attn(const float* __restrict__ qkv,
                                              float* __restrict__ out) {
  __shared__ float Qs[16 * 100];
  __shared__ float Ks[32 * 101];
  __shared__ float Ps[16 * 513];
  int bh = blockIdx.x;
  int b = bh >> 3, h = bh & 7;
  int q0 = blockIdx.y * 16;
  int tid = threadIdx.x;
  const float scale = 0.10206207261596577f;

  const float* qb = qkv + (size_t)(b * 512 + q0) * 2304 + h * 96;
  for (int i = tid; i < 16 * 96; i += 256) {
    int r = i / 96, c = i - r * 96;
    Qs[r * 100 + c] = qb[(size_t)r * 2304 + c];
  }
  int qi = tid >> 4, kseg = tid & 15;

  for (int kt = 0; kt < 16; ++kt) {
    __syncthreads();
    const float* kb = qkv + (size_t)(b * 512 + kt * 32) * 2304 + 768 + h * 96;
    for (int i = tid; i < 32 * 96; i += 256) {
      int r = i / 96, c = i - r * 96;
      Ks[r * 101 + c] = kb[(size_t)r * 2304 + c];
    }
    __syncthreads();
    int kj0 = kseg * 2;
    float s0 = 0.f, s1 = 0.f;
    const float* qrow = &Qs[qi * 100];
    const float* k0p = &Ks[kj0 * 101];
    const float* k1p = &Ks[(kj0 + 1) * 101];
#pragma unroll 8
    for (int d = 0; d < 96; ++d) {
      float qv = qrow[d];
      s0 += qv * k0p[d];
      s1 += qv * k1p[d];
    }
    Ps[qi * 513 + kt * 32 + kj0] = s0 * scale;
    Ps[qi * 513 + kt * 32 + kj0 + 1] = s1 * scale;
  }
  __syncthreads();

  {
    float m = -1e30f;
    for (int j = 0; j < 32; ++j) m = fmaxf(m, Ps[qi * 513 + kseg + j * 16]);
    m = fmaxf(m, __shfl_xor(m, 1)); m = fmaxf(m, __shfl_xor(m, 2));
    m = fmaxf(m, __shfl_xor(m, 4)); m = fmaxf(m, __shfl_xor(m, 8));
    float sum = 0.f;
    for (int j = 0; j < 32; ++j) {
      int idx = qi * 513 + kseg + j * 16;
      float e = expf(Ps[idx] - m);
      Ps[idx] = e;
      sum += e;
    }
    sum += __shfl_xor(sum, 1); sum += __shfl_xor(sum, 2);
    sum += __shfl_xor(sum, 4); sum += __shfl_xor(sum, 8);
    float inv = 1.f / sum;
    for (int j = 0; j < 32; ++j) Ps[qi * 513 + kseg + j * 16] *= inv;
  }

  float acc[6] = {0.f, 0.f, 0.f, 0.f, 0.f, 0.f};
  int d0 = kseg * 6;
  for (int kt = 0; kt < 16; ++kt) {
    __syncthreads();
    const float* vb = qkv + (size_t)(b * 512 + kt * 32) * 2304 + 1536 + h * 96;
    for (int i = tid; i < 32 * 96; i += 256) {
      int r = i / 96, c = i - r * 96;
      Ks[r * 101 + c] = vb[(size_t)r * 2304 + c];
    }
    __syncthreads();
#pragma unroll 4
    for (int kj = 0; kj < 32; ++kj) {
      float p = Ps[qi * 513 + kt * 32 + kj];
      const float* vrow = &Ks[kj * 101 + d0];
#pragma unroll
      for (int u = 0; u < 6; ++u) acc[u] += p * vrow[u];
    }
  }
  float* ob = out + (size_t)(b * 512 + q0 + qi) * 768 + h * 96 + d0;
#pragma unroll
  for (int u = 0; u < 6; ++u) ob[u] = acc[u];
}

// ---------------------------------------------------------------------------
// persistent BiLSTM recurrence (round-8 exact — measured floor). Used for
// layer 1 (gates precomputed) and as fallback.
// ---------------------------------------------------------------------------
#define NWGD 96
__global__ __launch_bounds__(256, 1) void k_lstm(const float* __restrict__ gates,
                                                 const float* __restrict__ Whh,
                                                 float* __restrict__ hbuf,
                                                 float* __restrict__ hs,
                                                 int* __restrict__ flags) {
  __shared__ float hlds[8 * 772];
  int tid = threadIdx.x;
  int wg = blockIdx.x;
  int dir = wg / NWGD;
  int grp = wg % NWGD;
  int rg = tid >> 5;
  int ks = tid & 31;

  float4 w4[4][6];
#pragma unroll
  for (int j = 0; j < 4; ++j) {
    const float* wp = Whh + ((size_t)dir * 3072 + j * 768 + grp * 8 + rg) * 768 + ks * 4;
#pragma unroll
    for (int jj = 0; jj < 6; ++jj)
      w4[j][jj] = *(const float4*)(wp + jj * 128);
  }

  float* hb = hbuf + (size_t)dir * 2 * 6144;
  const float* gbase = gates + (size_t)dir * 512 * 24576 + grp * 256 + tid;
  const float* hp = hlds + ks * 4;
  float cst = 0.f;

  for (int step = 0; step < 512; ++step) {
    int t = dir ? (511 - step) : step;
    float gqv = gbase[(size_t)t * 24576];

#pragma unroll
    for (int i = 0; i < 3; ++i) {
      int idx = i * 256 + tid;
      int b2 = idx / 96;
      int kq = (idx - b2 * 96) * 8;
      const u64* src = (const u64*)(hb + (step & 1) * 6144 + b2 * 768 + kq);
      u64 lo  = __hip_atomic_load(src + 0, __ATOMIC_RELAXED, __HIP_MEMORY_SCOPE_AGENT);
      u64 hi  = __hip_atomic_load(src + 1, __ATOMIC_RELAXED, __HIP_MEMORY_SCOPE_AGENT);
      u64 lo2 = __hip_atomic_load(src + 2, __ATOMIC_RELAXED, __HIP_MEMORY_SCOPE_AGENT);
      u64 hi2 = __hip_atomic_load(src + 3, __ATOMIC_RELAXED, __HIP_MEMORY_SCOPE_AGENT);
      float* dst = &hlds[b2 * 772 + kq];
      *(u64*)(dst + 0) = lo;
      *(u64*)(dst + 2) = hi;
      *(u64*)(dst + 4) = lo2;
      *(u64*)(dst + 6) = hi2;
    }
    __syncthreads();

    float v[32];
#pragma unroll
    for (int i = 0; i < 32; ++i) v[i] = 0.f;
#pragma unroll
    for (int jj = 0; jj < 6; ++jj) {
#pragma unroll
      for (int b2 = 0; b2 < 8; ++b2) {
        float4 hv = *(const float4*)(hp + b2 * 772 + jj * 128);
#pragma unroll
        for (int j = 0; j < 4; ++j) {
          float4 w = w4[j][jj];
          v[j * 8 + b2] = fmaf(w.x, hv.x, v[j * 8 + b2]);
          v[j * 8 + b2] = fmaf(w.y, hv.y, v[j * 8 + b2]);
          v[j * 8 + b2] = fmaf(w.z, hv.z, v[j * 8 + b2]);
          v[j * 8 + b2] = fmaf(w.w, hv.w, v[j * 8 + b2]);
        }
      }
    }

    {
      bool hi = (ks & 16) != 0;
#pragma unroll
      for (int i = 0; i < 16; ++i) {
        float keep = hi ? v[i + 16] : v[i];
        float send = hi ? v[i] : v[i + 16];
        v[i] = keep + __shfl_xor(send, 16);
      }
    }
    {
      bool hi = (ks & 8) != 0;
#pragma unroll
      for (int i = 0; i < 8; ++i) {
        float keep = hi ? v[i + 8] : v[i];
        float send = hi ? v[i] : v[i + 8];
        v[i] = keep + __shfl_xor(send, 8);
      }
    }
    {
      bool hi = (ks & 4) != 0;
#pragma unroll
      for (int i = 0; i < 4; ++i) {
        float keep = hi ? v[i + 4] : v[i];
        float send = hi ? v[i] : v[i + 4];
        v[i] = keep + __shfl_xor(send, 4);
      }
    }
    {
      bool hi = (ks & 2) != 0;
#pragma unroll
      for (int i = 0; i < 2; ++i) {
        float keep = hi ? v[i + 2] : v[i];
        float send = hi ? v[i] : v[i + 2];
        v[i] = keep + __shfl_xor(send, 2);
      }
    }
    {
      bool hi = (ks & 1) != 0;
      float keep = hi ? v[1] : v[0];
      float send = hi ? v[0] : v[1];
      v[0] = keep + __shfl_xor(send, 1);
    }

    float gv = v[0] + gqv;
    float gf = __shfl_down(gv, 8);
    float gg = __shfl_down(gv, 16);
    float go = __shfl_down(gv, 24);
    float hnew = 0.f;
    if (ks < 8) {
      float i_ = 1.f / (1.f + expf(-gv));
      float f_ = 1.f / (1.f + expf(-gf));
      float ci = tanhf(gg);
      float o_ = 1.f / (1.f + expf(-go));
      cst = f_ * cst + i_ * ci;
      hnew = o_ * tanhf(cst);
      __hip_atomic_store(hb + (size_t)((step + 1) & 1) * 6144 + ks * 768 + grp * 8 + rg,
                         hnew, __ATOMIC_RELAXED, __HIP_MEMORY_SCOPE_AGENT);
    }

    __syncthreads();
    if (tid == 0)
      __hip_atomic_store(&flags[wg * 32], step + 1, __ATOMIC_RELAXED, __HIP_MEMORY_SCOPE_AGENT);
    if (ks < 8)
      hs[((size_t)(ks * 512 + t)) * 1536 + dir * 768 + grp * 8 + rg] = hnew;
    if (tid < NWGD) {
      const int* fp = &flags[(dir * NWGD + tid) * 32];
      while (__hip_atomic_load(fp, __ATOMIC_RELAXED, __HIP_MEMORY_SCOPE_AGENT) <= step)
        __builtin_amdgcn_s_sleep(2);
    }
    __syncthreads();
  }
}

// ---------------------------------------------------------------------------
// layer-0 fused LSTM: gates computed on the fly (x1 @ Wih^T, fp32) in the
// barrier-propagation idle window. Wih WG-slice in LDS (98.8 KB); x staged
// per step; x-dot runs between flag release and poll (independent of h).
// hs written directly in split-bf16 layout [m][hi|lo|hi] for the l1 MFMA.
// Protocol identical to r8 k_lstm (measured floor).
// ---------------------------------------------------------------------------
__global__ __launch_bounds__(256, 1) void k_lstm_f0(const float* __restrict__ x,
                                                    const float* __restrict__ Wih,
                                                    const float* __restrict__ bih,
                                                    const float* __restrict__ Whh,
                                                    float* __restrict__ hbuf,
                                                    ushort_t* __restrict__ hs_bf,
                                                    int* __restrict__ flags) {
  __shared__ float hlds[8 * 772];     // 24.7 KB
  __shared__ float xlds[8 * 772];     // 24.7 KB
  __shared__ float wlds[32 * 772];    // 98.8 KB (row = j*8+rg)
  int tid = threadIdx.x;
  int wg = blockIdx.x;
  int dir = wg / NWGD;
  int grp = wg % NWGD;
  int rg = tid >> 5;
  int ks = tid & 31;

  // Whh in registers (as r8)
  float4 w4[4][6];
#pragma unroll
  for (int j = 0; j < 4; ++j) {
    const float* wp = Whh + ((size_t)dir * 3072 + j * 768 + grp * 8 + rg) * 768 + ks * 4;
#pragma unroll
    for (int jj = 0; jj < 6; ++jj)
      w4[j][jj] = *(const float4*)(wp + jj * 128);
  }
  // Wih slice -> LDS (32 rows x 768)
  for (int it = 0; it < 24; ++it) {
    int f4i = it * 256 + tid;           // 0..6143 float4
    int rowL = f4i / 192;
    int kq = (f4i - rowL * 192) * 4;
    int j = rowL >> 3, rgl = rowL & 7;
    float4 v = *(const float4*)(Wih + ((size_t)dir * 3072 + j * 768 + grp * 8 + rgl) * 768 + kq);
    *(float4*)&wlds[rowL * 772 + kq] = v;
  }
  float bi = bih[dir * 3072 + (ks >> 3) * 768 + grp * 8 + rg];

  float* hb = hbuf + (size_t)dir * 2 * 6144;
  const float* hp = hlds + ks * 4;
  float cst = 0.f;

  // prologue: xlds = x(t0); vx = x-dot(step 0); xreg = x(t1)
  int t0 = dir ? 511 : 0;
  for (int i = 0; i < 6; ++i) {
    int idx = i * 256 + tid;
    int b2 = idx / 192;
    int kq = (idx - b2 * 192) * 4;
    *(float4*)&xlds[b2 * 772 + kq] =
        *(const float4*)(x + ((size_t)(b2 * 512 + t0)) * 768 + kq);
  }
  __syncthreads();

  float vx[32];
#pragma unroll
  for (int i = 0; i < 32; ++i) vx[i] = 0.f;
#pragma unroll
  for (int jj = 0; jj < 6; ++jj) {
    float4 wv[4];
#pragma unroll
    for (int j = 0; j < 4; ++j)
      wv[j] = *(const float4*)&wlds[(j * 8 + rg) * 772 + jj * 128 + ks * 4];
#pragma unroll
    for (int b2 = 0; b2 < 8; ++b2) {
      float4 xv = *(const float4*)&xlds[b2 * 772 + jj * 128 + ks * 4];
#pragma unroll
      for (int j = 0; j < 4; ++j) {
        vx[j * 8 + b2] = fmaf(wv[j].x, xv.x, vx[j * 8 + b2]);
        vx[j * 8 + b2] = fmaf(wv[j].y, xv.y, vx[j * 8 + b2]);
        vx[j * 8 + b2] = fmaf(wv[j].z, xv.z, vx[j * 8 + b2]);
        vx[j * 8 + b2] = fmaf(wv[j].w, xv.w, vx[j * 8 + b2]);
      }
    }
  }
  float4 xreg[6];
  {
    int t1 = dir ? 510 : 1;
    for (int i = 0; i < 6; ++i) {
      int idx = i * 256 + tid;
      int b2 = idx / 192;
      int kq = (idx - b2 * 192) * 4;
      xreg[i] = *(const float4*)(x + ((size_t)(b2 * 512 + t1)) * 768 + kq);
    }
  }

  for (int step = 0; step < 512; ++step) {
    int t = dir ? (511 - step) : step;

    // stage h(step) via agent-scope u64 loads
#pragma unroll
    for (int i = 0; i < 3; ++i) {
      int idx = i * 256 + tid;
      int b2 = idx / 96;
      int kq = (idx - b2 * 96) * 8;
      const u64* src = (const u64*)(hb + (step & 1) * 6144 + b2 * 768 + kq);
      u64 lo  = __hip_atomic_load(src + 0, __ATOMIC_RELAXED, __HIP_MEMORY_SCOPE_AGENT);
      u64 hi  = __hip_atomic_load(src + 1, __ATOMIC_RELAXED, __HIP_MEMORY_SCOPE_AGENT);
      u64 lo2 = __hip_atomic_load(src + 2, __ATOMIC_RELAXED, __HIP_MEMORY_SCOPE_AGENT);
      u64 hi2 = __hip_atomic_load(src + 3, __ATOMIC_RELAXED, __HIP_MEMORY_SCOPE_AGENT);
      float* dst = &hlds[b2 * 772 + kq];
      *(u64*)(dst + 0) = lo;
      *(u64*)(dst + 2) = hi;
      *(u64*)(dst + 4) = lo2;
      *(u64*)(dst + 6) = hi2;
    }
    __syncthreads();   // A: hlds ready (also: all prior x-dot reads of xlds done)

    // xlds := x(t(step+1)) from xreg (read by x-dot after SYNC-B)
    if (step < 511) {
#pragma unroll
      for (int i = 0; i < 6; ++i) {
        int idx = i * 256 + tid;
        int b2 = idx / 192;
        int kq = (idx - b2 * 192) * 4;
        *(float4*)&xlds[b2 * 772 + kq] = xreg[i];
      }
    }

    // h-dot + merge x partials
    float v[32];
#pragma unroll
    for (int i = 0; i < 32; ++i) v[i] = vx[i];
#pragma unroll
    for (int jj = 0; jj < 6; ++jj) {
#pragma unroll
      for (int b2 = 0; b2 < 8; ++b2) {
        float4 hv = *(const float4*)(hp + b2 * 772 + jj * 128);
#pragma unroll
        for (int j = 0; j < 4; ++j) {
          float4 w = w4[j][jj];
          v[j * 8 + b2] = fmaf(w.x, hv.x, v[j * 8 + b2]);
          v[j * 8 + b2] = fmaf(w.y, hv.y, v[j * 8 + b2]);
          v[j * 8 + b2] = fmaf(w.z, hv.z, v[j * 8 + b2]);
          v[j * 8 + b2] = fmaf(w.w, hv.w, v[j * 8 + b2]);
        }
      }
    }

    // reduce-scatter (r8)
    {
      bool hi = (ks & 16) != 0;
#pragma unroll
      for (int i = 0; i < 16; ++i) {
        float keep = hi ? v[i + 16] : v[i];
        float send = hi ? v[i] : v[i + 16];
        v[i] = keep + __shfl_xor(send, 16);
      }
    }
    {
      bool hi = (ks & 8) != 0;
#pragma unroll
      for (int i = 0; i < 8; ++i) {
        float keep = hi ? v[i + 8] : v[i];
        float send = hi ? v[i] : v[i + 8];
        v[i] = keep + __shfl_xor(send, 8);
      }
    }
    {
      bool hi = (ks & 4) != 0;
#pragma unroll
      for (int i = 0; i < 4; ++i) {
        float keep = hi ? v[i + 4] : v[i];
        float send = hi ? v[i] : v[i + 4];
        v[i] = keep + __shfl_xor(send, 4);
      }
    }
    {
      bool hi = (ks & 2) != 0;
#pragma unroll
      for (int i = 0; i < 2; ++i) {
        float keep = hi ? v[i + 2] : v[i];
        float send = hi ? v[i] : v[i + 2];
        v[i] = keep + __shfl_xor(send, 2);
      }
    }
    {
      bool hi = (ks & 1) != 0;
      float keep = hi ? v[1] : v[0];
      float send = hi ? v[0] : v[1];
      v[0] = keep + __shfl_xor(send, 1);
    }

    float gv = v[0] + bi;
    float gf = __shfl_down(gv, 8);
    float gg = __shfl_down(gv, 16);
    float go = __shfl_down(gv, 24);
    float hnew = 0.f;
    if (ks < 8) {
      float i_ = 1.f / (1.f + expf(-gv));
      float f_ = 1.f / (1.f + expf(-gf));
      float ci = tanhf(gg);
      float o_ = 1.f / (1.f + expf(-go));
      cst = f_ * cst + i_ * ci;
      hnew = o_ * tanhf(cst);
      __hip_atomic_store(hb + (size_t)((step + 1) & 1) * 6144 + ks * 768 + grp * 8 + rg,
                         hnew, __ATOMIC_RELAXED, __HIP_MEMORY_SCOPE_AGENT);
    }

    __syncthreads();   // B: drains hb stores; xlds writes complete
    if (tid == 0)
      __hip_atomic_store(&flags[wg * 32], step + 1, __ATOMIC_RELAXED, __HIP_MEMORY_SCOPE_AGENT);
    if (ks < 8) {      // split-bf16 history store (off critical path)
      ushort_t hi16 = f2bf_bits(hnew);
      ushort_t lo16 = f2bf_bits(hnew - bf2f(hi16));
      size_t base = ((size_t)(ks * 512 + t)) * 4608 + dir * 768 + grp * 8 + rg;
      hs_bf[base] = hi16;
      hs_bf[base + 1536] = lo16;
      hs_bf[base + 3072] = hi16;
    }
    // idle-window work: x-dot for step+1 (independent of h), then next xreg
    if (step < 511) {
#pragma unroll
      for (int i = 0; i < 32; ++i) vx[i] = 0.f;
#pragma unroll
      for (int jj = 0; jj < 6; ++jj) {
        float4 wv[4];
#pragma unroll
        for (int j = 0; j < 4; ++j)
          wv[j] = *(const float4*)&wlds[(j * 8 + rg) * 772 + jj * 128 + ks * 4];
#pragma unroll
        for (int b2 = 0; b2 < 8; ++b2) {
          float4 xv = *(const float4*)&xlds[b2 * 772 + jj * 128 + ks * 4];
#pragma unroll
          for (int j = 0; j < 4; ++j) {
            vx[j * 8 + b2] = fmaf(wv[j].x, xv.x, vx[j * 8 + b2]);
            vx[j * 8 + b2] = fmaf(wv[j].y, xv.y, vx[j * 8 + b2]);
            vx[j * 8 + b2] = fmaf(wv[j].z, xv.z, vx[j * 8 + b2]);
            vx[j * 8 + b2] = fmaf(wv[j].w, xv.w, vx[j * 8 + b2]);
          }
        }
      }
    }
    if (step < 510) {
      int tn = dir ? (509 - step) : (step + 2);
#pragma unroll
      for (int i = 0; i < 6; ++i) {
        int idx = i * 256 + tid;
        int b2 = idx / 192;
        int kq = (idx - b2 * 192) * 4;
        xreg[i] = *(const float4*)(x + ((size_t)(b2 * 512 + tn)) * 768 + kq);
      }
    }
    if (tid < NWGD) {
      const int* fp = &flags[(dir * NWGD + tid) * 32];
      while (__hip_atomic_load(fp, __ATOMIC_RELAXED, __HIP_MEMORY_SCOPE_AGENT) <= step)
        __builtin_amdgcn_s_sleep(2);
    }
    __syncthreads();   // trailing
  }
}

// ---------------------------------------------------------------------------
// fc: em[4096][9]
// ---------------------------------------------------------------------------
__global__ __launch_bounds__(256) void k_fc(const float* __restrict__ A,
                                            const float* __restrict__ Wf,
                                            const float* __restrict__ bf,
                                            float* __restrict__ out) {
  __shared__ float Wl[9 * 1536];
  int tid = threadIdx.x;
  for (int i = tid; i < 9 * 1536; i += 256) Wl[i] = Wf[i];
  __syncthreads();
  int lane = tid & 63, wv = tid >> 6;
  int row = blockIdx.x * 4 + wv;
  const float* a = A + (size_t)row * 1536;
  float acc[9];
#pragma unroll
  for (int c = 0; c < 9; ++c) acc[c] = 0.f;
  for (int i = 0; i < 24; ++i) {
    float av = a[lane + i * 64];
#pragma unroll
    for (int c = 0; c < 9; ++c) acc[c] += av * Wl[c * 1536 + lane + i * 64];
  }
#pragma unroll
  for (int c = 0; c < 9; ++c) {
#pragma unroll
    for (int m = 1; m < 64; m <<= 1) acc[c] += __shfl_xor(acc[c], m);
  }
  if (lane == 0) {
#pragma unroll
    for (int c = 0; c < 9; ++c) out[(size_t)row * 9 + c] = acc[c] + bf[c];
  }
}

// ---------------------------------------------------------------------------
// CRF (round-8, sync-free recursion)
// ---------------------------------------------------------------------------
__global__ __launch_bounds__(512) void k_crf(const float* __restrict__ em,
                                             const int* __restrict__ labels,
                                             const float* __restrict__ cs,
                                             const float* __restrict__ ce,
                                             const float* __restrict__ ct,
                                             float* __restrict__ out) {
  __shared__ float trans_s[81];
  __shared__ unsigned char bps[8][511][12];
  __shared__ float partres[16];
  int tid = threadIdx.x;
  int b = tid >> 6;
  int lane = tid & 63;
  bool act = lane < 9;
  if (tid < 81) trans_s[tid] = ct[tid];
  __syncthreads();

  float tcol[9];
#pragma unroll
  for (int cp = 0; cp < 9; ++cp) tcol[cp] = act ? trans_s[cp * 9 + lane] : 0.f;

  float a_ = -1e30f, v_ = -1e30f;
  if (act) {
    float e0 = em[((size_t)b * 512) * 9 + lane];
    a_ = cs[lane] + e0;
    v_ = a_;
  }

  float e = act ? em[((size_t)b * 512 + 1) * 9 + lane] : 0.f;
  for (int t = 1; t < 512; ++t) {
    float e_nxt = 0.f;
    if (act && t < 511) e_nxt = em[((size_t)b * 512 + t + 1) * 9 + lane];
    float m = -1e30f, vm = -1e30f;
    int bp = 0;
    float xs[9];
#pragma unroll
    for (int cp = 0; cp < 9; ++cp) {
      float ap = __shfl(a_, cp);
      float vp = __shfl(v_, cp);
      float x = ap + tcol[cp];
      xs[cp] = x;
      m = fmaxf(m, x);
      float y = vp + tcol[cp];
      if (y > vm) { vm = y; bp = cp; }
    }
    float ssum = 0.f;
#pragma unroll
    for (int cp = 0; cp < 9; ++cp) ssum += expf(xs[cp] - m);
    if (act) {
      a_ = m + logf(ssum) + e;
      v_ = vm + e;
      bps[b][t - 1][lane] = (unsigned char)bp;
    }
    e = e_nxt;
  }

  float fin = act ? a_ + ce[lane] : -1e30f;
  float vfin = act ? v_ + ce[lane] : -1e30f;
  float m2 = fin;
  m2 = fmaxf(m2, __shfl_xor(m2, 1)); m2 = fmaxf(m2, __shfl_xor(m2, 2));
  m2 = fmaxf(m2, __shfl_xor(m2, 4)); m2 = fmaxf(m2, __shfl_xor(m2, 8));
  float s2 = expf(fin - m2);
  s2 += __shfl_xor(s2, 1); s2 += __shfl_xor(s2, 2);
  s2 += __shfl_xor(s2, 4); s2 += __shfl_xor(s2, 8);
  float logZ = m2 + logf(s2);

  float bv = vfin; int bi = lane;
#pragma unroll
  for (int s = 1; s < 16; s <<= 1) {
    float ov = __shfl_xor(bv, s);
    int oi = __shfl_xor(bi, s);
    if (ov > bv || (ov == bv && oi < bi)) { bv = ov; bi = oi; }
  }

  float np = 0.f;
  for (int t = lane; t < 512; t += 64) {
    int tg = labels[b * 512 + t];
    np += em[((size_t)b * 512 + t) * 9 + tg];
    if (t < 511) np += trans_s[tg * 9 + labels[b * 512 + t + 1]];
  }
#pragma unroll
  for (int s = 1; s < 64; s <<= 1) np += __shfl_xor(np, s);

  if (lane == 0) {
    np += cs[labels[b * 512]] + ce[labels[b * 512 + 511]];
    partres[b] = np;
    partres[8 + b] = logZ;
    out[1 + b * 512 + 511] = (float)bi;
    int tg = bi;
    for (int t = 510; t >= 0; --t) {
      tg = bps[b][t][tg];
      out[1 + b * 512 + t] = (float)tg;
    }
  }
  __syncthreads();
  if (tid == 0) {
    float acc = 0.f;
#pragma unroll
    for (int b2 = 0; b2 < 8; ++b2) acc += partres[b2] - partres[8 + b2];
    out[0] = -acc;
  }
}

// ---------------------------------------------------------------------------
extern "C" void kernel_launch(void* const* d_in, const int* in_sizes, int n_in,
                              void* d_out, int out_size, void* d_ws, size_t ws_size,
                              hipStream_t stream) {
  (void)in_sizes; (void)n_in; (void)out_size;
  const int*   ids    = (const int*)d_in[0];
  const int*   labels = (const int*)d_in[1];
  const float* emb    = (const float*)d_in[2];
  const float* hwWh   = (const float*)d_in[3];
  const float* hwbh   = (const float*)d_in[4];
  const float* hwWt   = (const float*)d_in[5];
  const float* hwbt   = (const float*)d_in[6];
  const float* ipw    = (const float*)d_in[7];
  const float* ipb    = (const float*)d_in[8];
  const float* opw    = (const float*)d_in[9];
  const float* opb    = (const float*)d_in[10];
  const float* l0Wih  = (const float*)d_in[11];
  const float* l0Whh  = (const float*)d_in[12];
  const float* l0b    = (const float*)d_in[13];
  const float* l1Wih  = (const float*)d_in[14];
  const float* l1Whh  = (const float*)d_in[15];
  const float* l1b    = (const float*)d_in[16];
  const float* fcW    = (const float*)d_in[17];
  const float* fcb    = (const float*)d_in[18];
  const float* cs     = (const float*)d_in[19];
  const float* ce     = (const float*)d_in[20];
  const float* ct     = (const float*)d_in[21];

  float* ws   = (float*)d_ws;
  float* x0   = ws;                 // 3,145,728
  float* gbuf = ws + 3145728;       // 25,165,824 (hh|tt, qkv, gates)
  float* hh   = gbuf;
  float* tt   = gbuf + 3145728;
  float* qkv  = gbuf + 6291456;
  float* x1   = ws + 28311552;      // 3,145,728
  float* hs0  = ws + 31457280;      // 6,291,456 (fallback path only)
  float* hs1  = ws + 37748736;      // 6,291,456
  float* em   = ws + 44040192;      // 36,864
  float* hbuf = ws + 44077056;      // 24,576
  int*   flags = (int*)(ws + 44101632);  // 192*32 ints
  ushort_t* bfA = (ushort_t*)(ws + 44107776);            // up to 4096*4608 shorts
  ushort_t* bfW = (ushort_t*)(ws + 44107776 + 9437184);  // up to 6144*4608 shorts
  const size_t ws_need = (44107776ull + 9437184ull + 14155776ull) * 4ull;
  bool bf16path = (ws_size >= ws_need);

  dim3 g768(6, 32), g2304(18, 32), g6144(48, 32);

  k_embed<<<BS_, 192, 0, stream>>>(ids, emb, x0);

  if (bf16path) {
    k_cvt<<<2048, 256, 0, stream>>>(x0, bfA, 768, BS_ * 768 / 4, 0);
    k_cvt<<<2048, 256, 0, stream>>>(hwWh, bfW, 768, 768 * 768 / 4, 1);
    k_mfma<<<g768, 256, 0, stream>>>(bfA, bfW, hwbh, hh, 768, 2304, 1, 0);
    k_cvt<<<2048, 256, 0, stream>>>(hwWt, bfW, 768, 768 * 768 / 4, 1);
    k_mfma<<<g768, 256, 0, stream>>>(bfA, bfW, hwbt, tt, 768, 2304, 2, 0);
    k_highway<<<768, 256, 0, stream>>>(x0, hh, tt);
    k_cvt<<<2048, 256, 0, stream>>>(x0, bfA, 768, BS_ * 768 / 4, 0);
    k_cvt<<<2048, 256, 0, stream>>>(ipw, bfW, 768, 2304 * 768 / 4, 1);
    k_mfma<<<g2304, 256, 0, stream>>>(bfA, bfW, ipb, qkv, 2304, 2304, 0, 0);
    k_attn<<<dim3(64, 32), 256, 0, stream>>>(qkv, x0);
    k_cvt<<<2048, 256, 0, stream>>>(x0, bfA, 768, BS_ * 768 / 4, 0);
    k_cvt<<<2048, 256, 0, stream>>>(opw, bfW, 768, 768 * 768 / 4, 1);
    k_mfma<<<g768, 256, 0, stream>>>(bfA, bfW, opb, x1, 768, 2304, 0, 0);

    // layer 0: fused gates LSTM (fp32 gates, hs0 written as split-bf16 -> bfA)
    hipMemsetAsync(hbuf, 0, (24576 + 192 * 32) * sizeof(float), stream);
    k_lstm_f0<<<192, 256, 0, stream>>>(x1, l0Wih, l0b, l0Whh, hbuf, bfA, flags);

    // layer 1 gates via MFMA (A = split hs0 from k_lstm_f0)
    k_cvt<<<4096, 256, 0, stream>>>(l1Wih, bfW, 1536, 6144 * 1536 / 4, 1);
    k_mfma<<<g6144, 256, 0, stream>>>(bfA, bfW, l1b, gbuf, 6144, 4608, 0, 1);
    hipMemsetAsync(hbuf, 0, (24576 + 192 * 32) * sizeof(float), stream);
    k_lstm<<<192, 256, 0, stream>>>(gbuf, l1Whh, hbuf, hs1, flags);
  } else {
    k_gemm<<<g768, 256, 0, stream>>>(x0, hwWh, hwbh, hh, BS_, 768, 768, 1, 0);
    k_gemm<<<g768, 256, 0, stream>>>(x0, hwWt, hwbt, tt, BS_, 768, 768, 2, 0);
    k_highway<<<768, 256, 0, stream>>>(x0, hh, tt);
    k_gemm<<<g2304, 256, 0, stream>>>(x0, ipw, ipb, qkv, BS_, 2304, 768, 0, 0);
    k_attn<<<dim3(64, 32), 256, 0, stream>>>(qkv, x0);
    k_gemm<<<g768, 256, 0, stream>>>(x0, opw, opb, x1, BS_, 768, 768, 0, 0);
    k_gemm<<<g6144, 256, 0, stream>>>(x1, l0Wih, l0b, gbuf, BS_, 6144, 768, 0, 1);
    hipMemsetAsync(hbuf, 0, (24576 + 192 * 32) * sizeof(float), stream);
    k_lstm<<<192, 256, 0, stream>>>(gbuf, l0Whh, hbuf, hs0, flags);
    k_gemm<<<g6144, 256, 0, stream>>>(hs0, l1Wih, l1b, gbuf, BS_, 6144, 1536, 0, 1);
    hipMemsetAsync(hbuf, 0, (24576 + 192 * 32) * sizeof(float), stream);
    k_lstm<<<192, 256, 0, stream>>>(gbuf, l1Whh, hbuf, hs1, flags);
  }

  k_fc<<<1024, 256, 0, stream>>>(hs1, fcW, fcb, em);
  k_crf<<<1, 512, 0, stream>>>(em, labels, cs, ce, ct, (float*)d_out);
}

// Round 14
// 7299.700 us; speedup vs baseline: 1.0699x; 1.0699x over previous
//
#include <hip/hip_runtime.h>
#include <hip/hip_bf16.h>
#include <cstdint>

#define B_   8
#define S_   512
#define D_   768
#define C_   9
#define BS_  4096   // B*S

typedef unsigned long long u64;
typedef unsigned short ushort_t;
typedef short bf16x8 __attribute__((ext_vector_type(8)));
typedef float f32x4 __attribute__((ext_vector_type(4)));
typedef __attribute__((address_space(1))) const void gvoid_t;
typedef __attribute__((address_space(3))) void svoid_t;

// ---------------------------------------------------------------------------
// embedding gather
// ---------------------------------------------------------------------------
__global__ __launch_bounds__(192) void k_embed(const int* __restrict__ ids,
                                               const float* __restrict__ emb,
                                               float* __restrict__ x) {
  int row = blockIdx.x;
  int id = ids[row];
  const float4* src = (const float4*)(emb + (size_t)id * D_);
  float4* dst = (float4*)(x + (size_t)row * D_);
  dst[threadIdx.x] = src[threadIdx.x];
}

// ---------------------------------------------------------------------------
// fp32 GEMM (single-buffer + XCD swizzle) — fallback path only.
// ---------------------------------------------------------------------------
#define GIDX(k, m) ((k)*144 + (m) + (((m) >> 5) << 2))

__global__ __launch_bounds__(256) void k_gemm(const float* __restrict__ A,
                                              const float* __restrict__ W,
                                              const float* __restrict__ bias,
                                              float* __restrict__ C,
                                              int M, int N, int K, int act, int mode) {
  __shared__ float As[2304];
  __shared__ float Bs[2304];
  int nwg = gridDim.x * gridDim.y;
  int lin = blockIdx.y * gridDim.x + blockIdx.x;
  int cpx = nwg >> 3;
  int swz = (lin & 7) * cpx + (lin >> 3);
  int bxs = swz % gridDim.x, bys = swz / gridDim.x;
  int bm0 = bys * 128, bn0 = bxs * 128;
  int tid = threadIdx.x;
  int tm = tid >> 4, tn = tid & 15;
  float acc[8][8];
#pragma unroll
  for (int i = 0; i < 8; ++i)
#pragma unroll
    for (int j = 0; j < 8; ++j) acc[i][j] = 0.f;

  for (int k0 = 0; k0 < K; k0 += 16) {
    __syncthreads();
#pragma unroll
    for (int j = 0; j < 2; ++j) {
      int f4 = tid + j * 256;
      int r = f4 >> 2;
      int kq = (f4 & 3) * 4;
      float4 va = *(const float4*)(A + (size_t)(bm0 + r) * K + k0 + kq);
      As[GIDX(kq + 0, r)] = va.x; As[GIDX(kq + 1, r)] = va.y;
      As[GIDX(kq + 2, r)] = va.z; As[GIDX(kq + 3, r)] = va.w;
      float4 vb = *(const float4*)(W + (size_t)(bn0 + r) * K + k0 + kq);
      Bs[GIDX(kq + 0, r)] = vb.x; Bs[GIDX(kq + 1, r)] = vb.y;
      Bs[GIDX(kq + 2, r)] = vb.z; Bs[GIDX(kq + 3, r)] = vb.w;
    }
    __syncthreads();
#pragma unroll
    for (int kk = 0; kk < 16; ++kk) {
      float a[8], b[8];
      *(float4*)&a[0] = *(const float4*)&As[GIDX(kk, tm * 8)];
      *(float4*)&a[4] = *(const float4*)&As[GIDX(kk, tm * 8 + 4)];
      *(float4*)&b[0] = *(const float4*)&Bs[GIDX(kk, tn * 8)];
      *(float4*)&b[4] = *(const float4*)&Bs[GIDX(kk, tn * 8 + 4)];
#pragma unroll
      for (int i = 0; i < 8; ++i)
#pragma unroll
        for (int j = 0; j < 8; ++j) acc[i][j] += a[i] * b[j];
    }
  }

  float bv[8];
#pragma unroll
  for (int j = 0; j < 8; ++j) bv[j] = bias[bn0 + tn * 8 + j];
#pragma unroll
  for (int i = 0; i < 8; ++i) {
    int row = bm0 + tm * 8 + i;
    float o[8];
#pragma unroll
    for (int j = 0; j < 8; ++j) {
      float v = acc[i][j] + bv[j];
      if (act == 1) v = fmaxf(v, 0.f);
      else if (act == 2) v = 1.f / (1.f + expf(-v));
      o[j] = v;
    }
    if (mode == 0) {
      float* cp = C + (size_t)row * N + bn0 + tn * 8;
      *(float4*)cp = make_float4(o[0], o[1], o[2], o[3]);
      *(float4*)(cp + 4) = make_float4(o[4], o[5], o[6], o[7]);
    } else {
      int bb = row >> 9, t = row & 511;
#pragma unroll
      for (int j = 0; j < 8; ++j) {
        unsigned n = bn0 + tn * 8 + j;
        unsigned dir = n / 3072u;
        unsigned n2 = n - dir * 3072u;
        unsigned g = n2 / 768u;
        unsigned rem = n2 - g * 768u;
        unsigned grp = rem >> 3, u = rem & 7;
        C[(((size_t)(dir * 512 + t) * 96 + grp) << 8) + u * 32 + g * 8 + bb] = o[j];
      }
    }
  }
}

// ---------------------------------------------------------------------------
// split-bf16 conversion: dst[m][3K] = mode0: [hi|lo|hi] (A)  mode1: [hi|hi|lo]
// ---------------------------------------------------------------------------
__device__ inline ushort_t f2bf_bits(float x) {
  __hip_bfloat16 h = __float2bfloat16(x);
  return __builtin_bit_cast(ushort_t, h);
}
__device__ inline float bf2f(ushort_t b) {
  return __bfloat162float(__builtin_bit_cast(__hip_bfloat16, b));
}

__global__ __launch_bounds__(256) void k_cvt(const float* __restrict__ src,
                                             ushort_t* __restrict__ dst,
                                             int K, int total4, int mode) {
  int kq4 = K >> 2;
  for (int idx = blockIdx.x * 256 + threadIdx.x; idx < total4; idx += gridDim.x * 256) {
    int m = idx / kq4;
    int kq = (idx - m * kq4) * 4;
    float4 v = *(const float4*)(src + (size_t)m * K + kq);
    ushort4 hi, lo;
    hi.x = f2bf_bits(v.x); lo.x = f2bf_bits(v.x - bf2f(hi.x));
    hi.y = f2bf_bits(v.y); lo.y = f2bf_bits(v.y - bf2f(hi.y));
    hi.z = f2bf_bits(v.z); lo.z = f2bf_bits(v.z - bf2f(hi.z));
    hi.w = f2bf_bits(v.w); lo.w = f2bf_bits(v.w - bf2f(hi.w));
    ushort_t* base = dst + (size_t)m * 3 * K + kq;
    *(ushort4*)(base)         = hi;
    *(ushort4*)(base + K)     = mode ? hi : lo;
    *(ushort4*)(base + 2 * K) = mode ? lo : hi;
  }
}

// ---------------------------------------------------------------------------
// bf16 MFMA GEMM (unified). C = A'[M][Kp] @ W'[N][Kp]^T + bias.
// mode 0: row-major C, act 0 none / 1 relu / 2 sigmoid /
//         3 highway-combine: C[m][n] = sig(v)*HH[m][n] + (1-sig(v))*X[m][n]
// mode 1: lstm-gates layout.
// ---------------------------------------------------------------------------
__global__ __launch_bounds__(256) void k_mfma(const ushort_t* __restrict__ A,
                                              const ushort_t* __restrict__ W,
                                              const float* __restrict__ bias,
                                              float* __restrict__ C,
                                              int N, int Kp, int act, int mode,
                                              const float* __restrict__ HH,
                                              const float* __restrict__ X) {
  __shared__ ushort_t Asb[128 * 64];
  __shared__ ushort_t Bsb[128 * 64];
  int nwg = gridDim.x * gridDim.y;
  int lin = blockIdx.y * gridDim.x + blockIdx.x;
  int cpx = nwg >> 3;
  int swz = (lin & 7) * cpx + (lin >> 3);
  int bn0 = (swz % gridDim.x) * 128, bm0 = (swz / gridDim.x) * 128;
  int tid = threadIdx.x;
  int w = tid >> 6, lane = tid & 63;
  int lr = lane & 15, lq = lane >> 4;

  f32x4 acc[2][8];
#pragma unroll
  for (int i = 0; i < 2; ++i)
#pragma unroll
    for (int j = 0; j < 8; ++j) acc[i][j] = (f32x4){0.f, 0.f, 0.f, 0.f};

  int srow0 = tid >> 3;
  int sc = tid & 7;

  for (int k0 = 0; k0 < Kp; k0 += 64) {
    __syncthreads();
#pragma unroll
    for (int it = 0; it < 4; ++it) {
      int row = it * 32 + srow0;
      int soff = (sc ^ (row & 7)) * 8;
      const ushort_t* ga = A + (size_t)(bm0 + row) * Kp + k0 + soff;
      const ushort_t* gb = W + (size_t)(bn0 + row) * Kp + k0 + soff;
      char* la = (char*)Asb + it * 4096 + (tid & 192) * 16;
      char* lb = (char*)Bsb + it * 4096 + (tid & 192) * 16;
      __builtin_amdgcn_global_load_lds((gvoid_t*)ga, (svoid_t*)la, 16, 0, 0);
      __builtin_amdgcn_global_load_lds((gvoid_t*)gb, (svoid_t*)lb, 16, 0, 0);
    }
    __syncthreads();
#pragma unroll
    for (int kf = 0; kf < 2; ++kf) {
      int c = kf * 4 + lq;
      int rowA0 = w * 32 + lr;
      int rowA1 = rowA0 + 16;
      bf16x8 a0 = *(const bf16x8*)&Asb[rowA0 * 64 + ((c ^ (rowA0 & 7)) << 3)];
      bf16x8 a1 = *(const bf16x8*)&Asb[rowA1 * 64 + ((c ^ (rowA1 & 7)) << 3)];
#pragma unroll
      for (int ns = 0; ns < 8; ++ns) {
        int rowB = ns * 16 + lr;
        bf16x8 b = *(const bf16x8*)&Bsb[rowB * 64 + ((c ^ (rowB & 7)) << 3)];
        acc[0][ns] = __builtin_amdgcn_mfma_f32_16x16x32_bf16(a0, b, acc[0][ns], 0, 0, 0);
        acc[1][ns] = __builtin_amdgcn_mfma_f32_16x16x32_bf16(a1, b, acc[1][ns], 0, 0, 0);
      }
    }
  }

  if (mode == 1) {
#pragma unroll
    for (int ns = 0; ns < 8; ++ns) {
      unsigned n = bn0 + ns * 16 + lr;
      unsigned dir = n / 3072u;
      unsigned n2 = n - dir * 3072u;
      unsigned g = n2 / 768u;
      unsigned rem = n2 - g * 768u;
      unsigned grp = rem >> 3, u = rem & 7;
      float bv = bias[n];
#pragma unroll
      for (int ms = 0; ms < 2; ++ms) {
#pragma unroll
        for (int r = 0; r < 4; ++r) {
          int m = bm0 + w * 32 + ms * 16 + lq * 4 + r;
          int bb = m >> 9, t = m & 511;
          C[(((size_t)(dir * 512 + t) * 96 + grp) << 8) + u * 32 + g * 8 + bb] =
              acc[ms][ns][r] + bv;
        }
      }
    }
  } else {
#pragma unroll
    for (int ns = 0; ns < 8; ++ns) {
      int col = bn0 + ns * 16 + lr;
      float bv = bias[col];
#pragma unroll
      for (int ms = 0; ms < 2; ++ms) {
#pragma unroll
        for (int r = 0; r < 4; ++r) {
          int m = bm0 + w * 32 + ms * 16 + lq * 4 + r;
          float v = acc[ms][ns][r] + bv;
          if (act == 1) v = fmaxf(v, 0.f);
          else if (act == 2) v = 1.f / (1.f + expf(-v));
          else if (act == 3) {
            float tv = 1.f / (1.f + expf(-v));
            float hhv = HH[(size_t)m * N + col];
            float xv = X[(size_t)m * N + col];
            v = tv * hhv + (1.f - tv) * xv;
          }
          C[(size_t)m * N + col] = v;
        }
      }
    }
  }
}

// ---------------------------------------------------------------------------
// highway combine (in place) — fallback path only
// ---------------------------------------------------------------------------
__global__ __launch_bounds__(256) void k_highway(float* __restrict__ x,
                                                 const float* __restrict__ hh,
                                                 const float* __restrict__ tt) {
  const int n4 = BS_ * D_ / 4;
  for (int i = blockIdx.x * 256 + threadIdx.x; i < n4; i += gridDim.x * 256) {
    float4 xv = ((const float4*)x)[i];
    float4 hv = ((const float4*)hh)[i];
    float4 tv = ((const float4*)tt)[i];
    xv.x = tv.x * hv.x + (1.f - tv.x) * xv.x;
    xv.y = tv.y * hv.y + (1.f - tv.y) * xv.y;
    xv.z = tv.z * hv.z + (1.f - tv.z) * xv.z;
    xv.w = tv.w * hv.w + (1.f - tv.w) * xv.w;
    ((float4*)x)[i] = xv;
  }
}

// ---------------------------------------------------------------------------
// multi-head attention (unchanged)
// ---------------------------------------------------------------------------
__global__ __launch_bounds__(256) void k_attn(const float* __restrict__ qkv,
                                              float* __restrict__ out) {
  __shared__ float Qs[16 * 100];
  __shared__ float Ks[32 * 101];
  __shared__ float Ps[16 * 513];
  int bh = blockIdx.x;
  int b = bh >> 3, h = bh & 7;
  int q0 = blockIdx.y * 16;
  int tid = threadIdx.x;
  const float scale = 0.10206207261596577f;

  const float* qb = qkv + (size_t)(b * 512 + q0) * 2304 + h * 96;
  for (int i = tid; i < 16 * 96; i += 256) {
    int r = i / 96, c = i - r * 96;
    Qs[r * 100 + c] = qb[(size_t)r * 2304 + c];
  }
  int qi = tid >> 4, kseg = tid & 15;

  for (int kt = 0; kt < 16; ++kt) {
    __syncthreads();
    const float* kb = qkv + (size_t)(b * 512 + kt * 32) * 2304 + 768 + h * 96;
    for (int i = tid; i < 32 * 96; i += 256) {
      int r = i / 96, c = i - r * 96;
      Ks[r * 101 + c] = kb[(size_t)r * 2304 + c];
    }
    __syncthreads();
    int kj0 = kseg * 2;
    float s0 = 0.f, s1 = 0.f;
    const float* qrow = &Qs[qi * 100];
    const float* k0p = &Ks[kj0 * 101];
    const float* k1p = &Ks[(kj0 + 1) * 101];
#pragma unroll 8
    for (int d = 0; d < 96; ++d) {
      float qv = qrow[d];
      s0 += qv * k0p[d];
      s1 += qv * k1p[d];
    }
    Ps[qi * 513 + kt * 32 + kj0] = s0 * scale;
    Ps[qi * 513 + kt * 32 + kj0 + 1] = s1 * scale;
  }
  __syncthreads();

  {
    float m = -1e30f;
    for (int j = 0; j < 32; ++j) m = fmaxf(m, Ps[qi * 513 + kseg + j * 16]);
    m = fmaxf(m, __shfl_xor(m, 1)); m = fmaxf(m, __shfl_xor(m, 2));
    m = fmaxf(m, __shfl_xor(m, 4)); m = fmaxf(m, __shfl_xor(m, 8));
    float sum = 0.f;
    for (int j = 0; j < 32; ++j) {
      int idx = qi * 513 + kseg + j * 16;
      float e = expf(Ps[idx] - m);
      Ps[idx] = e;
      sum += e;
    }
    sum += __shfl_xor(sum, 1); sum += __shfl_xor(sum, 2);
    sum += __shfl_xor(sum, 4); sum += __shfl_xor(sum, 8);
    float inv = 1.f / sum;
    for (int j = 0; j < 32; ++j) Ps[qi * 513 + kseg + j * 16] *= inv;
  }

  float acc[6] = {0.f, 0.f, 0.f, 0.f, 0.f, 0.f};
  int d0 = kseg * 6;
  for (int kt = 0; kt < 16; ++kt) {
    __syncthreads();
    const float* vb = qkv + (size_t)(b * 512 + kt * 32) * 2304 + 1536 + h * 96;
    for (int i = tid; i < 32 * 96; i += 256) {
      int r = i / 96, c = i - r * 96;
      Ks[r * 101 + c] = vb[(size_t)r * 2304 + c];
    }
    __syncthreads();
#pragma unroll 4
    for (int kj = 0; kj < 32; ++kj) {
      float p = Ps[qi * 513 + kt * 32 + kj];
      const float* vrow = &Ks[kj * 101 + d0];
#pragma unroll
      for (int u = 0; u < 6; ++u) acc[u] += p * vrow[u];
    }
  }
  float* ob = out + (size_t)(b * 512 + q0 + qi) * 768 + h * 96 + d0;
#pragma unroll
  for (int u = 0; u < 6; ++u) ob[u] = acc[u];
}

// ---------------------------------------------------------------------------
// persistent BiLSTM recurrence (round-8 exact — measured floor)
// ---------------------------------------------------------------------------
#define NWGD 96
__global__ __launch_bounds__(256, 1) void k_lstm(const float* __restrict__ gates,
                                                 const float* __restrict__ Whh,
                                                 float* __restrict__ hbuf,
                                                 float* __restrict__ hs,
                                                 int* __restrict__ flags) {
  __shared__ float hlds[8 * 772];
  int tid = threadIdx.x;
  int wg = blockIdx.x;
  int dir = wg / NWGD;
  int grp = wg % NWGD;
  int rg = tid >> 5;
  int ks = tid & 31;

  float4 w4[4][6];
#pragma unroll
  for (int j = 0; j < 4; ++j) {
    const float* wp = Whh + ((size_t)dir * 3072 + j * 768 + grp * 8 + rg) * 768 + ks * 4;
#pragma unroll
    for (int jj = 0; jj < 6; ++jj)
      w4[j][jj] = *(const float4*)(wp + jj * 128);
  }

  float* hb = hbuf + (size_t)dir * 2 * 6144;
  const float* gbase = gates + (size_t)dir * 512 * 24576 + grp * 256 + tid;
  const float* hp = hlds + ks * 4;
  float cst = 0.f;

  for (int step = 0; step < 512; ++step) {
    int t = dir ? (511 - step) : step;
    float gqv = gbase[(size_t)t * 24576];

#pragma unroll
    for (int i = 0; i < 3; ++i) {
      int idx = i * 256 + tid;
      int b2 = idx / 96;
      int kq = (idx - b2 * 96) * 8;
      const u64* src = (const u64*)(hb + (step & 1) * 6144 + b2 * 768 + kq);
      u64 lo  = __hip_atomic_load(src + 0, __ATOMIC_RELAXED, __HIP_MEMORY_SCOPE_AGENT);
      u64 hi  = __hip_atomic_load(src + 1, __ATOMIC_RELAXED, __HIP_MEMORY_SCOPE_AGENT);
      u64 lo2 = __hip_atomic_load(src + 2, __ATOMIC_RELAXED, __HIP_MEMORY_SCOPE_AGENT);
      u64 hi2 = __hip_atomic_load(src + 3, __ATOMIC_RELAXED, __HIP_MEMORY_SCOPE_AGENT);
      float* dst = &hlds[b2 * 772 + kq];
      *(u64*)(dst + 0) = lo;
      *(u64*)(dst + 2) = hi;
      *(u64*)(dst + 4) = lo2;
      *(u64*)(dst + 6) = hi2;
    }
    __syncthreads();

    float v[32];
#pragma unroll
    for (int i = 0; i < 32; ++i) v[i] = 0.f;
#pragma unroll
    for (int jj = 0; jj < 6; ++jj) {
#pragma unroll
      for (int b2 = 0; b2 < 8; ++b2) {
        float4 hv = *(const float4*)(hp + b2 * 772 + jj * 128);
#pragma unroll
        for (int j = 0; j < 4; ++j) {
          float4 w = w4[j][jj];
          v[j * 8 + b2] = fmaf(w.x, hv.x, v[j * 8 + b2]);
          v[j * 8 + b2] = fmaf(w.y, hv.y, v[j * 8 + b2]);
          v[j * 8 + b2] = fmaf(w.z, hv.z, v[j * 8 + b2]);
          v[j * 8 + b2] = fmaf(w.w, hv.w, v[j * 8 + b2]);
        }
      }
    }

    {
      bool hi = (ks & 16) != 0;
#pragma unroll
      for (int i = 0; i < 16; ++i) {
        float keep = hi ? v[i + 16] : v[i];
        float send = hi ? v[i] : v[i + 16];
        v[i] = keep + __shfl_xor(send, 16);
      }
    }
    {
      bool hi = (ks & 8) != 0;
#pragma unroll
      for (int i = 0; i < 8; ++i) {
        float keep = hi ? v[i + 8] : v[i];
        float send = hi ? v[i] : v[i + 8];
        v[i] = keep + __shfl_xor(send, 8);
      }
    }
    {
      bool hi = (ks & 4) != 0;
#pragma unroll
      for (int i = 0; i < 4; ++i) {
        float keep = hi ? v[i + 4] : v[i];
        float send = hi ? v[i] : v[i + 4];
        v[i] = keep + __shfl_xor(send, 4);
      }
    }
    {
      bool hi = (ks & 2) != 0;
#pragma unroll
      for (int i = 0; i < 2; ++i) {
        float keep = hi ? v[i + 2] : v[i];
        float send = hi ? v[i] : v[i + 2];
        v[i] = keep + __shfl_xor(send, 2);
      }
    }
    {
      bool hi = (ks & 1) != 0;
      float keep = hi ? v[1] : v[0];
      float send = hi ? v[0] : v[1];
      v[0] = keep + __shfl_xor(send, 1);
    }

    float gv = v[0] + gqv;
    float gf = __shfl_down(gv, 8);
    float gg = __shfl_down(gv, 16);
    float go = __shfl_down(gv, 24);
    float hnew = 0.f;
    if (ks < 8) {
      float i_ = 1.f / (1.f + expf(-gv));
      float f_ = 1.f / (1.f + expf(-gf));
      float ci = tanhf(gg);
      float o_ = 1.f / (1.f + expf(-go));
      cst = f_ * cst + i_ * ci;
      hnew = o_ * tanhf(cst);
      __hip_atomic_store(hb + (size_t)((step + 1) & 1) * 6144 + ks * 768 + grp * 8 + rg,
                         hnew, __ATOMIC_RELAXED, __HIP_MEMORY_SCOPE_AGENT);
    }

    __syncthreads();
    if (tid == 0)
      __hip_atomic_store(&flags[wg * 32], step + 1, __ATOMIC_RELAXED, __HIP_MEMORY_SCOPE_AGENT);
    if (ks < 8)
      hs[((size_t)(ks * 512 + t)) * 1536 + dir * 768 + grp * 8 + rg] = hnew;
    if (tid < NWGD) {
      const int* fp = &flags[(dir * NWGD + tid) * 32];
      while (__hip_atomic_load(fp, __ATOMIC_RELAXED, __HIP_MEMORY_SCOPE_AGENT) <= step)
        __builtin_amdgcn_s_sleep(2);
    }
    __syncthreads();
  }
}

// ---------------------------------------------------------------------------
// fc: em[4096][9]
// ---------------------------------------------------------------------------
__global__ __launch_bounds__(256) void k_fc(const float* __restrict__ A,
                                            const float* __restrict__ Wf,
                                            const float* __restrict__ bf,
                                            float* __restrict__ out) {
  __shared__ float Wl[9 * 1536];
  int tid = threadIdx.x;
  for (int i = tid; i < 9 * 1536; i += 256) Wl[i] = Wf[i];
  __syncthreads();
  int lane = tid & 63, wv = tid >> 6;
  int row = blockIdx.x * 4 + wv;
  const float* a = A + (size_t)row * 1536;
  float acc[9];
#pragma unroll
  for (int c = 0; c < 9; ++c) acc[c] = 0.f;
  for (int i = 0; i < 24; ++i) {
    float av = a[lane + i * 64];
#pragma unroll
    for (int c = 0; c < 9; ++c) acc[c] += av * Wl[c * 1536 + lane + i * 64];
  }
#pragma unroll
  for (int c = 0; c < 9; ++c) {
#pragma unroll
    for (int m = 1; m < 64; m <<= 1) acc[c] += __shfl_xor(acc[c], m);
  }
  if (lane == 0) {
#pragma unroll
    for (int c = 0; c < 9; ++c) out[(size_t)row * 9 + c] = acc[c] + bf[c];
  }
}

// ---------------------------------------------------------------------------
// CRF (round-8, sync-free recursion)
// ---------------------------------------------------------------------------
__global__ __launch_bounds__(512) void k_crf(const float* __restrict__ em,
                                             const int* __restrict__ labels,
                                             const float* __restrict__ cs,
                                             const float* __restrict__ ce,
                                             const float* __restrict__ ct,
                                             float* __restrict__ out) {
  __shared__ float trans_s[81];
  __shared__ unsigned char bps[8][511][12];
  __shared__ float partres[16];
  int tid = threadIdx.x;
  int b = tid >> 6;
  int lane = tid & 63;
  bool act = lane < 9;
  if (tid < 81) trans_s[tid] = ct[tid];
  __syncthreads();

  float tcol[9];
#pragma unroll
  for (int cp = 0; cp < 9; ++cp) tcol[cp] = act ? trans_s[cp * 9 + lane] : 0.f;

  float a_ = -1e30f, v_ = -1e30f;
  if (act) {
    float e0 = em[((size_t)b * 512) * 9 + lane];
    a_ = cs[lane] + e0;
    v_ = a_;
  }

  float e = act ? em[((size_t)b * 512 + 1) * 9 + lane] : 0.f;
  for (int t = 1; t < 512; ++t) {
    float e_nxt = 0.f;
    if (act && t < 511) e_nxt = em[((size_t)b * 512 + t + 1) * 9 + lane];
    float m = -1e30f, vm = -1e30f;
    int bp = 0;
    float xs[9];
#pragma unroll
    for (int cp = 0; cp < 9; ++cp) {
      float ap = __shfl(a_, cp);
      float vp = __shfl(v_, cp);
      float x = ap + tcol[cp];
      xs[cp] = x;
      m = fmaxf(m, x);
      float y = vp + tcol[cp];
      if (y > vm) { vm = y; bp = cp; }
    }
    float ssum = 0.f;
#pragma unroll
    for (int cp = 0; cp < 9; ++cp) ssum += expf(xs[cp] - m);
    if (act) {
      a_ = m + logf(ssum) + e;
      v_ = vm + e;
      bps[b][t - 1][lane] = (unsigned char)bp;
    }
    e = e_nxt;
  }

  float fin = act ? a_ + ce[lane] : -1e30f;
  float vfin = act ? v_ + ce[lane] : -1e30f;
  float m2 = fin;
  m2 = fmaxf(m2, __shfl_xor(m2, 1)); m2 = fmaxf(m2, __shfl_xor(m2, 2));
  m2 = fmaxf(m2, __shfl_xor(m2, 4)); m2 = fmaxf(m2, __shfl_xor(m2, 8));
  float s2 = expf(fin - m2);
  s2 += __shfl_xor(s2, 1); s2 += __shfl_xor(s2, 2);
  s2 += __shfl_xor(s2, 4); s2 += __shfl_xor(s2, 8);
  float logZ = m2 + logf(s2);

  float bv = vfin; int bi = lane;
#pragma unroll
  for (int s = 1; s < 16; s <<= 1) {
    float ov = __shfl_xor(bv, s);
    int oi = __shfl_xor(bi, s);
    if (ov > bv || (ov == bv && oi < bi)) { bv = ov; bi = oi; }
  }

  float np = 0.f;
  for (int t = lane; t < 512; t += 64) {
    int tg = labels[b * 512 + t];
    np += em[((size_t)b * 512 + t) * 9 + tg];
    if (t < 511) np += trans_s[tg * 9 + labels[b * 512 + t + 1]];
  }
#pragma unroll
  for (int s = 1; s < 64; s <<= 1) np += __shfl_xor(np, s);

  if (lane == 0) {
    np += cs[labels[b * 512]] + ce[labels[b * 512 + 511]];
    partres[b] = np;
    partres[8 + b] = logZ;
    out[1 + b * 512 + 511] = (float)bi;
    int tg = bi;
    for (int t = 510; t >= 0; --t) {
      tg = bps[b][t][tg];
      out[1 + b * 512 + t] = (float)tg;
    }
  }
  __syncthreads();
  if (tid == 0) {
    float acc = 0.f;
#pragma unroll
    for (int b2 = 0; b2 < 8; ++b2) acc += partres[b2] - partres[8 + b2];
    out[0] = -acc;
  }
}

// ---------------------------------------------------------------------------
extern "C" void kernel_launch(void* const* d_in, const int* in_sizes, int n_in,
                              void* d_out, int out_size, void* d_ws, size_t ws_size,
                              hipStream_t stream) {
  (void)in_sizes; (void)n_in; (void)out_size;
  const int*   ids    = (const int*)d_in[0];
  const int*   labels = (const int*)d_in[1];
  const float* emb    = (const float*)d_in[2];
  const float* hwWh   = (const float*)d_in[3];
  const float* hwbh   = (const float*)d_in[4];
  const float* hwWt   = (const float*)d_in[5];
  const float* hwbt   = (const float*)d_in[6];
  const float* ipw    = (const float*)d_in[7];
  const float* ipb    = (const float*)d_in[8];
  const float* opw    = (const float*)d_in[9];
  const float* opb    = (const float*)d_in[10];
  const float* l0Wih  = (const float*)d_in[11];
  const float* l0Whh  = (const float*)d_in[12];
  const float* l0b    = (const float*)d_in[13];
  const float* l1Wih  = (const float*)d_in[14];
  const float* l1Whh  = (const float*)d_in[15];
  const float* l1b    = (const float*)d_in[16];
  const float* fcW    = (const float*)d_in[17];
  const float* fcb    = (const float*)d_in[18];
  const float* cs     = (const float*)d_in[19];
  const float* ce     = (const float*)d_in[20];
  const float* ct     = (const float*)d_in[21];

  float* ws   = (float*)d_ws;
  float* x0   = ws;                 // 3,145,728
  float* gbuf = ws + 3145728;       // 25,165,824 (hh|tt, qkv, gates)
  float* hh   = gbuf;
  float* tt   = gbuf + 3145728;
  float* qkv  = gbuf + 6291456;
  float* x1   = ws + 28311552;      // 3,145,728
  float* hs0  = ws + 31457280;      // 6,291,456
  float* hs1  = ws + 37748736;      // 6,291,456
  float* em   = ws + 44040192;      // 36,864
  float* hbuf = ws + 44077056;      // 24,576
  int*   flags = (int*)(ws + 44101632);  // 192*32 ints
  ushort_t* bfA = (ushort_t*)(ws + 44107776);            // up to 4096*4608 shorts
  ushort_t* bfW = (ushort_t*)(ws + 44107776 + 9437184);  // up to 6144*4608 shorts
  const size_t ws_need = (44107776ull + 9437184ull + 14155776ull) * 4ull;
  bool bf16path = (ws_size >= ws_need);

  dim3 g768(6, 32), g2304(18, 32), g6144(48, 32);

  k_embed<<<BS_, 192, 0, stream>>>(ids, emb, x0);

  if (bf16path) {
    k_cvt<<<2048, 256, 0, stream>>>(x0, bfA, 768, BS_ * 768 / 4, 0);
    k_cvt<<<2048, 256, 0, stream>>>(hwWh, bfW, 768, 768 * 768 / 4, 1);
    k_mfma<<<g768, 256, 0, stream>>>(bfA, bfW, hwbh, hh, 768, 2304, 1, 0, nullptr, nullptr);
    k_cvt<<<2048, 256, 0, stream>>>(hwWt, bfW, 768, 768 * 768 / 4, 1);
    // fused: x0 = sig(x0@hwWt^T+b)*hh + (1-sig)*x0   (highway combine in epilogue)
    k_mfma<<<g768, 256, 0, stream>>>(bfA, bfW, hwbt, x0, 768, 2304, 3, 0, hh, x0);
    k_cvt<<<2048, 256, 0, stream>>>(x0, bfA, 768, BS_ * 768 / 4, 0);
    k_cvt<<<2048, 256, 0, stream>>>(ipw, bfW, 768, 2304 * 768 / 4, 1);
    k_mfma<<<g2304, 256, 0, stream>>>(bfA, bfW, ipb, qkv, 2304, 2304, 0, 0, nullptr, nullptr);
    k_attn<<<dim3(64, 32), 256, 0, stream>>>(qkv, x0);
    k_cvt<<<2048, 256, 0, stream>>>(x0, bfA, 768, BS_ * 768 / 4, 0);
    k_cvt<<<2048, 256, 0, stream>>>(opw, bfW, 768, 768 * 768 / 4, 1);
    k_mfma<<<g768, 256, 0, stream>>>(bfA, bfW, opb, x1, 768, 2304, 0, 0, nullptr, nullptr);
    // layer-0 gates
    k_cvt<<<2048, 256, 0, stream>>>(x1, bfA, 768, BS_ * 768 / 4, 0);
    k_cvt<<<2048, 256, 0, stream>>>(l0Wih, bfW, 768, 6144 * 768 / 4, 1);
    k_mfma<<<g6144, 256, 0, stream>>>(bfA, bfW, l0b, gbuf, 6144, 2304, 0, 1, nullptr, nullptr);
  } else {
    k_gemm<<<g768, 256, 0, stream>>>(x0, hwWh, hwbh, hh, BS_, 768, 768, 1, 0);
    k_gemm<<<g768, 256, 0, stream>>>(x0, hwWt, hwbt, tt, BS_, 768, 768, 2, 0);
    k_highway<<<768, 256, 0, stream>>>(x0, hh, tt);
    k_gemm<<<g2304, 256, 0, stream>>>(x0, ipw, ipb, qkv, BS_, 2304, 768, 0, 0);
    k_attn<<<dim3(64, 32), 256, 0, stream>>>(qkv, x0);
    k_gemm<<<g768, 256, 0, stream>>>(x0, opw, opb, x1, BS_, 768, 768, 0, 0);
    k_gemm<<<g6144, 256, 0, stream>>>(x1, l0Wih, l0b, gbuf, BS_, 6144, 768, 0, 1);
  }
  hipMemsetAsync(hbuf, 0, (24576 + 192 * 32) * sizeof(float), stream);
  k_lstm<<<192, 256, 0, stream>>>(gbuf, l0Whh, hbuf, hs0, flags);

  // layer-1 gates
  if (bf16path) {
    k_cvt<<<2048, 256, 0, stream>>>(hs0, bfA, 1536, BS_ * 1536 / 4, 0);
    k_cvt<<<4096, 256, 0, stream>>>(l1Wih, bfW, 1536, 6144 * 1536 / 4, 1);
    k_mfma<<<g6144, 256, 0, stream>>>(bfA, bfW, l1b, gbuf, 6144, 4608, 0, 1, nullptr, nullptr);
  } else {
    k_gemm<<<g6144, 256, 0, stream>>>(hs0, l1Wih, l1b, gbuf, BS_, 6144, 1536, 0, 1);
  }
  hipMemsetAsync(hbuf, 0, (24576 + 192 * 32) * sizeof(float), stream);
  k_lstm<<<192, 256, 0, stream>>>(gbuf, l1Whh, hbuf, hs1, flags);

  k_fc<<<1024, 256, 0, stream>>>(hs1, fcW, fcb, em);
  k_crf<<<1, 512, 0, stream>>>(em, labels, cs, ce, ct, (float*)d_out);
}

// Round 15
// 7169.139 us; speedup vs baseline: 1.0893x; 1.0182x over previous
//
#include <hip/hip_runtime.h>
#include <hip/hip_bf16.h>
#include <cstdint>

#define B_   8
#define S_   512
#define D_   768
#define C_   9
#define BS_  4096   // B*S

typedef unsigned long long u64;
typedef unsigned short ushort_t;
typedef short bf16x8 __attribute__((ext_vector_type(8)));
typedef float f32x4 __attribute__((ext_vector_type(4)));
typedef __attribute__((address_space(1))) const void gvoid_t;
typedef __attribute__((address_space(3))) void svoid_t;

// ---------------------------------------------------------------------------
// embedding gather
// ---------------------------------------------------------------------------
__global__ __launch_bounds__(192) void k_embed(const int* __restrict__ ids,
                                               const float* __restrict__ emb,
                                               float* __restrict__ x) {
  int row = blockIdx.x;
  int id = ids[row];
  const float4* src = (const float4*)(emb + (size_t)id * D_);
  float4* dst = (float4*)(x + (size_t)row * D_);
  dst[threadIdx.x] = src[threadIdx.x];
}

// ---------------------------------------------------------------------------
// fp32 GEMM (single-buffer + XCD swizzle) — fallback path only.
// ---------------------------------------------------------------------------
#define GIDX(k, m) ((k)*144 + (m) + (((m) >> 5) << 2))

__global__ __launch_bounds__(256) void k_gemm(const float* __restrict__ A,
                                              const float* __restrict__ W,
                                              const float* __restrict__ bias,
                                              float* __restrict__ C,
                                              int M, int N, int K, int act, int mode) {
  __shared__ float As[2304];
  __shared__ float Bs[2304];
  int nwg = gridDim.x * gridDim.y;
  int lin = blockIdx.y * gridDim.x + blockIdx.x;
  int cpx = nwg >> 3;
  int swz = (lin & 7) * cpx + (lin >> 3);
  int bxs = swz % gridDim.x, bys = swz / gridDim.x;
  int bm0 = bys * 128, bn0 = bxs * 128;
  int tid = threadIdx.x;
  int tm = tid >> 4, tn = tid & 15;
  float acc[8][8];
#pragma unroll
  for (int i = 0; i < 8; ++i)
#pragma unroll
    for (int j = 0; j < 8; ++j) acc[i][j] = 0.f;

  for (int k0 = 0; k0 < K; k0 += 16) {
    __syncthreads();
#pragma unroll
    for (int j = 0; j < 2; ++j) {
      int f4 = tid + j * 256;
      int r = f4 >> 2;
      int kq = (f4 & 3) * 4;
      float4 va = *(const float4*)(A + (size_t)(bm0 + r) * K + k0 + kq);
      As[GIDX(kq + 0, r)] = va.x; As[GIDX(kq + 1, r)] = va.y;
      As[GIDX(kq + 2, r)] = va.z; As[GIDX(kq + 3, r)] = va.w;
      float4 vb = *(const float4*)(W + (size_t)(bn0 + r) * K + k0 + kq);
      Bs[GIDX(kq + 0, r)] = vb.x; Bs[GIDX(kq + 1, r)] = vb.y;
      Bs[GIDX(kq + 2, r)] = vb.z; Bs[GIDX(kq + 3, r)] = vb.w;
    }
    __syncthreads();
#pragma unroll
    for (int kk = 0; kk < 16; ++kk) {
      float a[8], b[8];
      *(float4*)&a[0] = *(const float4*)&As[GIDX(kk, tm * 8)];
      *(float4*)&a[4] = *(const float4*)&As[GIDX(kk, tm * 8 + 4)];
      *(float4*)&b[0] = *(const float4*)&Bs[GIDX(kk, tn * 8)];
      *(float4*)&b[4] = *(const float4*)&Bs[GIDX(kk, tn * 8 + 4)];
#pragma unroll
      for (int i = 0; i < 8; ++i)
#pragma unroll
        for (int j = 0; j < 8; ++j) acc[i][j] += a[i] * b[j];
    }
  }

  float bv[8];
#pragma unroll
  for (int j = 0; j < 8; ++j) bv[j] = bias[bn0 + tn * 8 + j];
#pragma unroll
  for (int i = 0; i < 8; ++i) {
    int row = bm0 + tm * 8 + i;
    float o[8];
#pragma unroll
    for (int j = 0; j < 8; ++j) {
      float v = acc[i][j] + bv[j];
      if (act == 1) v = fmaxf(v, 0.f);
      else if (act == 2) v = 1.f / (1.f + expf(-v));
      o[j] = v;
    }
    if (mode == 0) {
      float* cp = C + (size_t)row * N + bn0 + tn * 8;
      *(float4*)cp = make_float4(o[0], o[1], o[2], o[3]);
      *(float4*)(cp + 4) = make_float4(o[4], o[5], o[6], o[7]);
    } else {
      int bb = row >> 9, t = row & 511;
#pragma unroll
      for (int j = 0; j < 8; ++j) {
        unsigned n = bn0 + tn * 8 + j;
        unsigned dir = n / 3072u;
        unsigned n2 = n - dir * 3072u;
        unsigned g = n2 / 768u;
        unsigned rem = n2 - g * 768u;
        unsigned grp = rem >> 3, u = rem & 7;
        C[(((size_t)(dir * 512 + t) * 96 + grp) << 8) + u * 32 + g * 8 + bb] = o[j];
      }
    }
  }
}

// ---------------------------------------------------------------------------
// split-bf16 conversion: dst[m][3K] = mode0: [hi|lo|hi] (A)  mode1: [hi|hi|lo]
// ---------------------------------------------------------------------------
__device__ inline ushort_t f2bf_bits(float x) {
  __hip_bfloat16 h = __float2bfloat16(x);
  return __builtin_bit_cast(ushort_t, h);
}
__device__ inline float bf2f(ushort_t b) {
  return __bfloat162float(__builtin_bit_cast(__hip_bfloat16, b));
}

__global__ __launch_bounds__(256) void k_cvt(const float* __restrict__ src,
                                             ushort_t* __restrict__ dst,
                                             int K, int total4, int mode) {
  int kq4 = K >> 2;
  for (int idx = blockIdx.x * 256 + threadIdx.x; idx < total4; idx += gridDim.x * 256) {
    int m = idx / kq4;
    int kq = (idx - m * kq4) * 4;
    float4 v = *(const float4*)(src + (size_t)m * K + kq);
    ushort4 hi, lo;
    hi.x = f2bf_bits(v.x); lo.x = f2bf_bits(v.x - bf2f(hi.x));
    hi.y = f2bf_bits(v.y); lo.y = f2bf_bits(v.y - bf2f(hi.y));
    hi.z = f2bf_bits(v.z); lo.z = f2bf_bits(v.z - bf2f(hi.z));
    hi.w = f2bf_bits(v.w); lo.w = f2bf_bits(v.w - bf2f(hi.w));
    ushort_t* base = dst + (size_t)m * 3 * K + kq;
    *(ushort4*)(base)         = hi;
    *(ushort4*)(base + K)     = mode ? hi : lo;
    *(ushort4*)(base + 2 * K) = mode ? lo : hi;
  }
}

// ---------------------------------------------------------------------------
// bf16 MFMA GEMM (unified). C = A'[M][Kp] @ W'[N][Kp]^T + bias.
// mode 0: row-major C with act; mode 1: lstm-gates layout.
// Staging via global_load_lds width=16: pre-swizzled global source + linear
// LDS dest; reads use the same XOR chunk swizzle c^(row&7) (involution).
// ---------------------------------------------------------------------------
__global__ __launch_bounds__(256) void k_mfma(const ushort_t* __restrict__ A,
                                              const ushort_t* __restrict__ W,
                                              const float* __restrict__ bias,
                                              float* __restrict__ C,
                                              int N, int Kp, int act, int mode) {
  __shared__ ushort_t Asb[128 * 64];
  __shared__ ushort_t Bsb[128 * 64];
  int nwg = gridDim.x * gridDim.y;
  int lin = blockIdx.y * gridDim.x + blockIdx.x;
  int cpx = nwg >> 3;
  int swz = (lin & 7) * cpx + (lin >> 3);
  int bn0 = (swz % gridDim.x) * 128, bm0 = (swz / gridDim.x) * 128;
  int tid = threadIdx.x;
  int w = tid >> 6, lane = tid & 63;
  int lr = lane & 15, lq = lane >> 4;

  f32x4 acc[2][8];
#pragma unroll
  for (int i = 0; i < 2; ++i)
#pragma unroll
    for (int j = 0; j < 8; ++j) acc[i][j] = (f32x4){0.f, 0.f, 0.f, 0.f};

  int srow0 = tid >> 3;
  int sc = tid & 7;

  for (int k0 = 0; k0 < Kp; k0 += 64) {
    __syncthreads();
#pragma unroll
    for (int it = 0; it < 4; ++it) {
      int row = it * 32 + srow0;
      int soff = (sc ^ (row & 7)) * 8;
      const ushort_t* ga = A + (size_t)(bm0 + row) * Kp + k0 + soff;
      const ushort_t* gb = W + (size_t)(bn0 + row) * Kp + k0 + soff;
      char* la = (char*)Asb + it * 4096 + (tid & 192) * 16;
      char* lb = (char*)Bsb + it * 4096 + (tid & 192) * 16;
      __builtin_amdgcn_global_load_lds((gvoid_t*)ga, (svoid_t*)la, 16, 0, 0);
      __builtin_amdgcn_global_load_lds((gvoid_t*)gb, (svoid_t*)lb, 16, 0, 0);
    }
    __syncthreads();
#pragma unroll
    for (int kf = 0; kf < 2; ++kf) {
      int c = kf * 4 + lq;
      int rowA0 = w * 32 + lr;
      int rowA1 = rowA0 + 16;
      bf16x8 a0 = *(const bf16x8*)&Asb[rowA0 * 64 + ((c ^ (rowA0 & 7)) << 3)];
      bf16x8 a1 = *(const bf16x8*)&Asb[rowA1 * 64 + ((c ^ (rowA1 & 7)) << 3)];
#pragma unroll
      for (int ns = 0; ns < 8; ++ns) {
        int rowB = ns * 16 + lr;
        bf16x8 b = *(const bf16x8*)&Bsb[rowB * 64 + ((c ^ (rowB & 7)) << 3)];
        acc[0][ns] = __builtin_amdgcn_mfma_f32_16x16x32_bf16(a0, b, acc[0][ns], 0, 0, 0);
        acc[1][ns] = __builtin_amdgcn_mfma_f32_16x16x32_bf16(a1, b, acc[1][ns], 0, 0, 0);
      }
    }
  }

  if (mode == 1) {
#pragma unroll
    for (int ns = 0; ns < 8; ++ns) {
      unsigned n = bn0 + ns * 16 + lr;
      unsigned dir = n / 3072u;
      unsigned n2 = n - dir * 3072u;
      unsigned g = n2 / 768u;
      unsigned rem = n2 - g * 768u;
      unsigned grp = rem >> 3, u = rem & 7;
      float bv = bias[n];
#pragma unroll
      for (int ms = 0; ms < 2; ++ms) {
#pragma unroll
        for (int r = 0; r < 4; ++r) {
          int m = bm0 + w * 32 + ms * 16 + lq * 4 + r;
          int bb = m >> 9, t = m & 511;
          C[(((size_t)(dir * 512 + t) * 96 + grp) << 8) + u * 32 + g * 8 + bb] =
              acc[ms][ns][r] + bv;
        }
      }
    }
  } else {
#pragma unroll
    for (int ns = 0; ns < 8; ++ns) {
      int col = bn0 + ns * 16 + lr;
      float bv = bias[col];
#pragma unroll
      for (int ms = 0; ms < 2; ++ms) {
#pragma unroll
        for (int r = 0; r < 4; ++r) {
          int m = bm0 + w * 32 + ms * 16 + lq * 4 + r;
          float v = acc[ms][ns][r] + bv;
          if (act == 1) v = fmaxf(v, 0.f);
          else if (act == 2) v = 1.f / (1.f + expf(-v));
          C[(size_t)m * N + col] = v;
        }
      }
    }
  }
}

// ---------------------------------------------------------------------------
// highway combine (in place)
// ---------------------------------------------------------------------------
__global__ __launch_bounds__(256) void k_highway(float* __restrict__ x,
                                                 const float* __restrict__ hh,
                                                 const float* __restrict__ tt) {
  const int n4 = BS_ * D_ / 4;
  for (int i = blockIdx.x * 256 + threadIdx.x; i < n4; i += gridDim.x * 256) {
    float4 xv = ((const float4*)x)[i];
    float4 hv = ((const float4*)hh)[i];
    float4 tv = ((const float4*)tt)[i];
    xv.x = tv.x * hv.x + (1.f - tv.x) * xv.x;
    xv.y = tv.y * hv.y + (1.f - tv.y) * xv.y;
    xv.z = tv.z * hv.z + (1.f - tv.z) * xv.z;
    xv.w = tv.w * hv.w + (1.f - tv.w) * xv.w;
    ((float4*)x)[i] = xv;
  }
}

// ---------------------------------------------------------------------------
// multi-head attention
// ---------------------------------------------------------------------------
__global__ __launch_bounds__(256) void k_attn(const float* __restrict__ qkv,
                                              float* __restrict__ out) {
  __shared__ float Qs[16 * 100];
  __shared__ float Ks[32 * 101];
  __shared__ float Ps[16 * 513];
  int bh = blockIdx.x;
  int b = bh >> 3, h = bh & 7;
  int q0 = blockIdx.y * 16;
  int tid = threadIdx.x;
  const float scale = 0.10206207261596577f;

  const float* qb = qkv + (size_t)(b * 512 + q0) * 2304 + h * 96;
  for (int i = tid; i < 16 * 96; i += 256) {
    int r = i / 96, c = i - r * 96;
    Qs[r * 100 + c] = qb[(size_t)r * 2304 + c];
  }
  int qi = tid >> 4, kseg = tid & 15;

  for (int kt = 0; kt < 16; ++kt) {
    __syncthreads();
    const float* kb = qkv + (size_t)(b * 512 + kt * 32) * 2304 + 768 + h * 96;
    for (int i = tid; i < 32 * 96; i += 256) {
      int r = i / 96, c = i - r * 96;
      Ks[r * 101 + c] = kb[(size_t)r * 2304 + c];
    }
    __syncthreads();
    int kj0 = kseg * 2;
    float s0 = 0.f, s1 = 0.f;
    const float* qrow = &Qs[qi * 100];
    const float* k0p = &Ks[kj0 * 101];
    const float* k1p = &Ks[(kj0 + 1) * 101];
#pragma unroll 8
    for (int d = 0; d < 96; ++d) {
      float qv = qrow[d];
      s0 += qv * k0p[d];
      s1 += qv * k1p[d];
    }
    Ps[qi * 513 + kt * 32 + kj0] = s0 * scale;
    Ps[qi * 513 + kt * 32 + kj0 + 1] = s1 * scale;
  }
  __syncthreads();

  {
    float m = -1e30f;
    for (int j = 0; j < 32; ++j) m = fmaxf(m, Ps[qi * 513 + kseg + j * 16]);
    m = fmaxf(m, __shfl_xor(m, 1)); m = fmaxf(m, __shfl_xor(m, 2));
    m = fmaxf(m, __shfl_xor(m, 4)); m = fmaxf(m, __shfl_xor(m, 8));
    float sum = 0.f;
    for (int j = 0; j < 32; ++j) {
      int idx = qi * 513 + kseg + j * 16;
      float e = expf(Ps[idx] - m);
      Ps[idx] = e;
      sum += e;
    }
    sum += __shfl_xor(sum, 1); sum += __shfl_xor(sum, 2);
    sum += __shfl_xor(sum, 4); sum += __shfl_xor(sum, 8);
    float inv = 1.f / sum;
    for (int j = 0; j < 32; ++j) Ps[qi * 513 + kseg + j * 16] *= inv;
  }

  float acc[6] = {0.f, 0.f, 0.f, 0.f, 0.f, 0.f};
  int d0 = kseg * 6;
  for (int kt = 0; kt < 16; ++kt) {
    __syncthreads();
    const float* vb = qkv + (size_t)(b * 512 + kt * 32) * 2304 + 1536 + h * 96;
    for (int i = tid; i < 32 * 96; i += 256) {
      int r = i / 96, c = i - r * 96;
      Ks[r * 101 + c] = vb[(size_t)r * 2304 + c];
    }
    __syncthreads();
#pragma unroll 4
    for (int kj = 0; kj < 32; ++kj) {
      float p = Ps[qi * 513 + kt * 32 + kj];
      const float* vrow = &Ks[kj * 101 + d0];
#pragma unroll
      for (int u = 0; u < 6; ++u) acc[u] += p * vrow[u];
    }
  }
  float* ob = out + (size_t)(b * 512 + q0 + qi) * 768 + h * 96 + d0;
#pragma unroll
  for (int u = 0; u < 6; ++u) ob[u] = acc[u];
}

// ---------------------------------------------------------------------------
// persistent BiLSTM recurrence (round-8 exact — measured floor)
// ---------------------------------------------------------------------------
#define NWGD 96
__global__ __launch_bounds__(256, 1) void k_lstm(const float* __restrict__ gates,
                                                 const float* __restrict__ Whh,
                                                 float* __restrict__ hbuf,
                                                 float* __restrict__ hs,
                                                 int* __restrict__ flags) {
  __shared__ float hlds[8 * 772];
  int tid = threadIdx.x;
  int wg = blockIdx.x;
  int dir = wg / NWGD;
  int grp = wg % NWGD;
  int rg = tid >> 5;
  int ks = tid & 31;

  float4 w4[4][6];
#pragma unroll
  for (int j = 0; j < 4; ++j) {
    const float* wp = Whh + ((size_t)dir * 3072 + j * 768 + grp * 8 + rg) * 768 + ks * 4;
#pragma unroll
    for (int jj = 0; jj < 6; ++jj)
      w4[j][jj] = *(const float4*)(wp + jj * 128);
  }

  float* hb = hbuf + (size_t)dir * 2 * 6144;
  const float* gbase = gates + (size_t)dir * 512 * 24576 + grp * 256 + tid;
  const float* hp = hlds + ks * 4;
  float cst = 0.f;

  for (int step = 0; step < 512; ++step) {
    int t = dir ? (511 - step) : step;
    float gqv = gbase[(size_t)t * 24576];

#pragma unroll
    for (int i = 0; i < 3; ++i) {
      int idx = i * 256 + tid;
      int b2 = idx / 96;
      int kq = (idx - b2 * 96) * 8;
      const u64* src = (const u64*)(hb + (step & 1) * 6144 + b2 * 768 + kq);
      u64 lo  = __hip_atomic_load(src + 0, __ATOMIC_RELAXED, __HIP_MEMORY_SCOPE_AGENT);
      u64 hi  = __hip_atomic_load(src + 1, __ATOMIC_RELAXED, __HIP_MEMORY_SCOPE_AGENT);
      u64 lo2 = __hip_atomic_load(src + 2, __ATOMIC_RELAXED, __HIP_MEMORY_SCOPE_AGENT);
      u64 hi2 = __hip_atomic_load(src + 3, __ATOMIC_RELAXED, __HIP_MEMORY_SCOPE_AGENT);
      float* dst = &hlds[b2 * 772 + kq];
      *(u64*)(dst + 0) = lo;
      *(u64*)(dst + 2) = hi;
      *(u64*)(dst + 4) = lo2;
      *(u64*)(dst + 6) = hi2;
    }
    __syncthreads();

    float v[32];
#pragma unroll
    for (int i = 0; i < 32; ++i) v[i] = 0.f;
#pragma unroll
    for (int jj = 0; jj < 6; ++jj) {
#pragma unroll
      for (int b2 = 0; b2 < 8; ++b2) {
        float4 hv = *(const float4*)(hp + b2 * 772 + jj * 128);
#pragma unroll
        for (int j = 0; j < 4; ++j) {
          float4 w = w4[j][jj];
          v[j * 8 + b2] = fmaf(w.x, hv.x, v[j * 8 + b2]);
          v[j * 8 + b2] = fmaf(w.y, hv.y, v[j * 8 + b2]);
          v[j * 8 + b2] = fmaf(w.z, hv.z, v[j * 8 + b2]);
          v[j * 8 + b2] = fmaf(w.w, hv.w, v[j * 8 + b2]);
        }
      }
    }

    {
      bool hi = (ks & 16) != 0;
#pragma unroll
      for (int i = 0; i < 16; ++i) {
        float keep = hi ? v[i + 16] : v[i];
        float send = hi ? v[i] : v[i + 16];
        v[i] = keep + __shfl_xor(send, 16);
      }
    }
    {
      bool hi = (ks & 8) != 0;
#pragma unroll
      for (int i = 0; i < 8; ++i) {
        float keep = hi ? v[i + 8] : v[i];
        float send = hi ? v[i] : v[i + 8];
        v[i] = keep + __shfl_xor(send, 8);
      }
    }
    {
      bool hi = (ks & 4) != 0;
#pragma unroll
      for (int i = 0; i < 4; ++i) {
        float keep = hi ? v[i + 4] : v[i];
        float send = hi ? v[i] : v[i + 4];
        v[i] = keep + __shfl_xor(send, 4);
      }
    }
    {
      bool hi = (ks & 2) != 0;
#pragma unroll
      for (int i = 0; i < 2; ++i) {
        float keep = hi ? v[i + 2] : v[i];
        float send = hi ? v[i] : v[i + 2];
        v[i] = keep + __shfl_xor(send, 2);
      }
    }
    {
      bool hi = (ks & 1) != 0;
      float keep = hi ? v[1] : v[0];
      float send = hi ? v[0] : v[1];
      v[0] = keep + __shfl_xor(send, 1);
    }

    float gv = v[0] + gqv;
    float gf = __shfl_down(gv, 8);
    float gg = __shfl_down(gv, 16);
    float go = __shfl_down(gv, 24);
    float hnew = 0.f;
    if (ks < 8) {
      float i_ = 1.f / (1.f + expf(-gv));
      float f_ = 1.f / (1.f + expf(-gf));
      float ci = tanhf(gg);
      float o_ = 1.f / (1.f + expf(-go));
      cst = f_ * cst + i_ * ci;
      hnew = o_ * tanhf(cst);
      __hip_atomic_store(hb + (size_t)((step + 1) & 1) * 6144 + ks * 768 + grp * 8 + rg,
                         hnew, __ATOMIC_RELAXED, __HIP_MEMORY_SCOPE_AGENT);
    }

    __syncthreads();
    if (tid == 0)
      __hip_atomic_store(&flags[wg * 32], step + 1, __ATOMIC_RELAXED, __HIP_MEMORY_SCOPE_AGENT);
    if (ks < 8)
      hs[((size_t)(ks * 512 + t)) * 1536 + dir * 768 + grp * 8 + rg] = hnew;
    if (tid < NWGD) {
      const int* fp = &flags[(dir * NWGD + tid) * 32];
      while (__hip_atomic_load(fp, __ATOMIC_RELAXED, __HIP_MEMORY_SCOPE_AGENT) <= step)
        __builtin_amdgcn_s_sleep(2);
    }
    __syncthreads();
  }
}

// ---------------------------------------------------------------------------
// fc: em[4096][9]
// ---------------------------------------------------------------------------
__global__ __launch_bounds__(256) void k_fc(const float* __restrict__ A,
                                            const float* __restrict__ Wf,
                                            const float* __restrict__ bf,
                                            float* __restrict__ out) {
  __shared__ float Wl[9 * 1536];
  int tid = threadIdx.x;
  for (int i = tid; i < 9 * 1536; i += 256) Wl[i] = Wf[i];
  __syncthreads();
  int lane = tid & 63, wv = tid >> 6;
  int row = blockIdx.x * 4 + wv;
  const float* a = A + (size_t)row * 1536;
  float acc[9];
#pragma unroll
  for (int c = 0; c < 9; ++c) acc[c] = 0.f;
  for (int i = 0; i < 24; ++i) {
    float av = a[lane + i * 64];
#pragma unroll
    for (int c = 0; c < 9; ++c) acc[c] += av * Wl[c * 1536 + lane + i * 64];
  }
#pragma unroll
  for (int c = 0; c < 9; ++c) {
#pragma unroll
    for (int m = 1; m < 64; m <<= 1) acc[c] += __shfl_xor(acc[c], m);
  }
  if (lane == 0) {
#pragma unroll
    for (int c = 0; c < 9; ++c) out[(size_t)row * 9 + c] = acc[c] + bf[c];
  }
}

// ---------------------------------------------------------------------------
// CRF (sync-free recursion)
// ---------------------------------------------------------------------------
__global__ __launch_bounds__(512) void k_crf(const float* __restrict__ em,
                                             const int* __restrict__ labels,
                                             const float* __restrict__ cs,
                                             const float* __restrict__ ce,
                                             const float* __restrict__ ct,
                                             float* __restrict__ out) {
  __shared__ float trans_s[81];
  __shared__ unsigned char bps[8][511][12];
  __shared__ float partres[16];
  int tid = threadIdx.x;
  int b = tid >> 6;
  int lane = tid & 63;
  bool act = lane < 9;
  if (tid < 81) trans_s[tid] = ct[tid];
  __syncthreads();

  float tcol[9];
#pragma unroll
  for (int cp = 0; cp < 9; ++cp) tcol[cp] = act ? trans_s[cp * 9 + lane] : 0.f;

  float a_ = -1e30f, v_ = -1e30f;
  if (act) {
    float e0 = em[((size_t)b * 512) * 9 + lane];
    a_ = cs[lane] + e0;
    v_ = a_;
  }

  float e = act ? em[((size_t)b * 512 + 1) * 9 + lane] : 0.f;
  for (int t = 1; t < 512; ++t) {
    float e_nxt = 0.f;
    if (act && t < 511) e_nxt = em[((size_t)b * 512 + t + 1) * 9 + lane];
    float m = -1e30f, vm = -1e30f;
    int bp = 0;
    float xs[9];
#pragma unroll
    for (int cp = 0; cp < 9; ++cp) {
      float ap = __shfl(a_, cp);
      float vp = __shfl(v_, cp);
      float x = ap + tcol[cp];
      xs[cp] = x;
      m = fmaxf(m, x);
      float y = vp + tcol[cp];
      if (y > vm) { vm = y; bp = cp; }
    }
    float ssum = 0.f;
#pragma unroll
    for (int cp = 0; cp < 9; ++cp) ssum += expf(xs[cp] - m);
    if (act) {
      a_ = m + logf(ssum) + e;
      v_ = vm + e;
      bps[b][t - 1][lane] = (unsigned char)bp;
    }
    e = e_nxt;
  }

  float fin = act ? a_ + ce[lane] : -1e30f;
  float vfin = act ? v_ + ce[lane] : -1e30f;
  float m2 = fin;
  m2 = fmaxf(m2, __shfl_xor(m2, 1)); m2 = fmaxf(m2, __shfl_xor(m2, 2));
  m2 = fmaxf(m2, __shfl_xor(m2, 4)); m2 = fmaxf(m2, __shfl_xor(m2, 8));
  float s2 = expf(fin - m2);
  s2 += __shfl_xor(s2, 1); s2 += __shfl_xor(s2, 2);
  s2 += __shfl_xor(s2, 4); s2 += __shfl_xor(s2, 8);
  float logZ = m2 + logf(s2);

  float bv = vfin; int bi = lane;
#pragma unroll
  for (int s = 1; s < 16; s <<= 1) {
    float ov = __shfl_xor(bv, s);
    int oi = __shfl_xor(bi, s);
    if (ov > bv || (ov == bv && oi < bi)) { bv = ov; bi = oi; }
  }

  float np = 0.f;
  for (int t = lane; t < 512; t += 64) {
    int tg = labels[b * 512 + t];
    np += em[((size_t)b * 512 + t) * 9 + tg];
    if (t < 511) np += trans_s[tg * 9 + labels[b * 512 + t + 1]];
  }
#pragma unroll
  for (int s = 1; s < 64; s <<= 1) np += __shfl_xor(np, s);

  if (lane == 0) {
    np += cs[labels[b * 512]] + ce[labels[b * 512 + 511]];
    partres[b] = np;
    partres[8 + b] = logZ;
    out[1 + b * 512 + 511] = (float)bi;
    int tg = bi;
    for (int t = 510; t >= 0; --t) {
      tg = bps[b][t][tg];
      out[1 + b * 512 + t] = (float)tg;
    }
  }
  __syncthreads();
  if (tid == 0) {
    float acc = 0.f;
#pragma unroll
    for (int b2 = 0; b2 < 8; ++b2) acc += partres[b2] - partres[8 + b2];
    out[0] = -acc;
  }
}

// ---------------------------------------------------------------------------
extern "C" void kernel_launch(void* const* d_in, const int* in_sizes, int n_in,
                              void* d_out, int out_size, void* d_ws, size_t ws_size,
                              hipStream_t stream) {
  (void)in_sizes; (void)n_in; (void)out_size;
  const int*   ids    = (const int*)d_in[0];
  const int*   labels = (const int*)d_in[1];
  const float* emb    = (const float*)d_in[2];
  const float* hwWh   = (const float*)d_in[3];
  const float* hwbh   = (const float*)d_in[4];
  const float* hwWt   = (const float*)d_in[5];
  const float* hwbt   = (const float*)d_in[6];
  const float* ipw    = (const float*)d_in[7];
  const float* ipb    = (const float*)d_in[8];
  const float* opw    = (const float*)d_in[9];
  const float* opb    = (const float*)d_in[10];
  const float* l0Wih  = (const float*)d_in[11];
  const float* l0Whh  = (const float*)d_in[12];
  const float* l0b    = (const float*)d_in[13];
  const float* l1Wih  = (const float*)d_in[14];
  const float* l1Whh  = (const float*)d_in[15];
  const float* l1b    = (const float*)d_in[16];
  const float* fcW    = (const float*)d_in[17];
  const float* fcb    = (const float*)d_in[18];
  const float* cs     = (const float*)d_in[19];
  const float* ce     = (const float*)d_in[20];
  const float* ct     = (const float*)d_in[21];

  float* ws   = (float*)d_ws;
  float* x0   = ws;                 // 3,145,728
  float* gbuf = ws + 3145728;       // 25,165,824 (hh|tt, qkv, gates)
  float* hh   = gbuf;
  float* tt   = gbuf + 3145728;
  float* qkv  = gbuf + 6291456;
  float* x1   = ws + 28311552;      // 3,145,728
  float* hs0  = ws + 31457280;      // 6,291,456
  float* hs1  = ws + 37748736;      // 6,291,456
  float* em   = ws + 44040192;      // 36,864
  float* hbuf = ws + 44077056;      // 24,576
  int*   flags = (int*)(ws + 44101632);  // 192*32 ints
  ushort_t* bfA = (ushort_t*)(ws + 44107776);            // up to 4096*4608 shorts
  ushort_t* bfW = (ushort_t*)(ws + 44107776 + 9437184);  // up to 6144*4608 shorts
  const size_t ws_need = (44107776ull + 9437184ull + 14155776ull) * 4ull;
  bool bf16path = (ws_size >= ws_need);

  dim3 g768(6, 32), g2304(18, 32), g6144(48, 32);

  k_embed<<<BS_, 192, 0, stream>>>(ids, emb, x0);

  if (bf16path) {
    k_cvt<<<2048, 256, 0, stream>>>(x0, bfA, 768, BS_ * 768 / 4, 0);
    k_cvt<<<2048, 256, 0, stream>>>(hwWh, bfW, 768, 768 * 768 / 4, 1);
    k_mfma<<<g768, 256, 0, stream>>>(bfA, bfW, hwbh, hh, 768, 2304, 1, 0);
    k_cvt<<<2048, 256, 0, stream>>>(hwWt, bfW, 768, 768 * 768 / 4, 1);
    k_mfma<<<g768, 256, 0, stream>>>(bfA, bfW, hwbt, tt, 768, 2304, 2, 0);
    k_highway<<<768, 256, 0, stream>>>(x0, hh, tt);
    k_cvt<<<2048, 256, 0, stream>>>(x0, bfA, 768, BS_ * 768 / 4, 0);
    k_cvt<<<2048, 256, 0, stream>>>(ipw, bfW, 768, 2304 * 768 / 4, 1);
    k_mfma<<<g2304, 256, 0, stream>>>(bfA, bfW, ipb, qkv, 2304, 2304, 0, 0);
    k_attn<<<dim3(64, 32), 256, 0, stream>>>(qkv, x0);
    k_cvt<<<2048, 256, 0, stream>>>(x0, bfA, 768, BS_ * 768 / 4, 0);
    k_cvt<<<2048, 256, 0, stream>>>(opw, bfW, 768, 768 * 768 / 4, 1);
    k_mfma<<<g768, 256, 0, stream>>>(bfA, bfW, opb, x1, 768, 2304, 0, 0);
    k_cvt<<<2048, 256, 0, stream>>>(x1, bfA, 768, BS_ * 768 / 4, 0);
    k_cvt<<<2048, 256, 0, stream>>>(l0Wih, bfW, 768, 6144 * 768 / 4, 1);
    k_mfma<<<g6144, 256, 0, stream>>>(bfA, bfW, l0b, gbuf, 6144, 2304, 0, 1);
  } else {
    k_gemm<<<g768, 256, 0, stream>>>(x0, hwWh, hwbh, hh, BS_, 768, 768, 1, 0);
    k_gemm<<<g768, 256, 0, stream>>>(x0, hwWt, hwbt, tt, BS_, 768, 768, 2, 0);
    k_highway<<<768, 256, 0, stream>>>(x0, hh, tt);
    k_gemm<<<g2304, 256, 0, stream>>>(x0, ipw, ipb, qkv, BS_, 2304, 768, 0, 0);
    k_attn<<<dim3(64, 32), 256, 0, stream>>>(qkv, x0);
    k_gemm<<<g768, 256, 0, stream>>>(x0, opw, opb, x1, BS_, 768, 768, 0, 0);
    k_gemm<<<g6144, 256, 0, stream>>>(x1, l0Wih, l0b, gbuf, BS_, 6144, 768, 0, 1);
  }
  hipMemsetAsync(hbuf, 0, (24576 + 192 * 32) * sizeof(float), stream);
  k_lstm<<<192, 256, 0, stream>>>(gbuf, l0Whh, hbuf, hs0, flags);

  if (bf16path) {
    k_cvt<<<2048, 256, 0, stream>>>(hs0, bfA, 1536, BS_ * 1536 / 4, 0);
    k_cvt<<<4096, 256, 0, stream>>>(l1Wih, bfW, 1536, 6144 * 1536 / 4, 1);
    k_mfma<<<g6144, 256, 0, stream>>>(bfA, bfW, l1b, gbuf, 6144, 4608, 0, 1);
  } else {
    k_gemm<<<g6144, 256, 0, stream>>>(hs0, l1Wih, l1b, gbuf, BS_, 6144, 1536, 0, 1);
  }
  hipMemsetAsync(hbuf, 0, (24576 + 192 * 32) * sizeof(float), stream);
  k_lstm<<<192, 256, 0, stream>>>(gbuf, l1Whh, hbuf, hs1, flags);

  k_fc<<<1024, 256, 0, stream>>>(hs1, fcW, fcb, em);
  k_crf<<<1, 512, 0, stream>>>(em, labels, cs, ce, ct, (float*)d_out);
}